// Round 6
// baseline (8941.357 us; speedup 1.0000x reference)
//
#include <hip/hip_runtime.h>
#include <hip/hip_bf16.h>
#include <math.h>

#define HW   511
#define HW2  261121      // 511*511
#define MM   510
#define MM2  260100      // 510*510
#define NN   512
#define NN2  262144      // 512*512
#define PI_D 3.14159265358979323846

typedef __attribute__((ext_vector_type(8))) short short8;
typedef __attribute__((ext_vector_type(4))) float float4v;

__device__ __forceinline__ float bf2f(const __hip_bfloat16 v) { return __bfloat162float(v); }

// dual-mode input read: mode=0 -> bf16 storage, mode=1 -> float32 storage
__device__ __forceinline__ float ldin(const void* p, long i, int mode)
{
    return mode ? ((const float*)p)[i] : bf2f(((const __hip_bfloat16*)p)[i]);
}

// fp32 -> bf16 (round-to-nearest-even), as raw short
__device__ __forceinline__ short f2bf(float v)
{
    unsigned u = __builtin_bit_cast(unsigned, v);
    u += 0x7FFF + ((u >> 16) & 1);
    return (short)(u >> 16);
}
__device__ __forceinline__ float bfs2f(short s)
{
    unsigned u = ((unsigned)(unsigned short)s) << 16;
    return __builtin_bit_cast(float, u);
}

// probe input storage dtype (proved mode=1/f32 on this harness; kept graph-safe)
__global__ void detect_kernel(const void* __restrict__ f, int* __restrict__ mode)
{
    __shared__ int cnt;
    if (threadIdx.x == 0) cnt = 0;
    __syncthreads();
    float v = ((const float*)f)[threadIdx.x];
    float a = fabsf(v);
    int sane = (isfinite(v) && a > 1e-6f && a < 100.f) ? 1 : 0;
    atomicAdd(&cnt, sane);
    __syncthreads();
    if (threadIdx.x == 0) mode[0] = (cnt >= 128) ? 1 : 0;
}

__global__ void sentinel_kernel(float* __restrict__ out) { out[0] = 0.25f; }

__global__ void zerof_kernel(float* __restrict__ p, long n)
{
    long i = (long)blockIdx.x * 256 + threadIdx.x;
    if (i < n) p[i] = 0.f;
}

__global__ void zerod_kernel(double* __restrict__ p)
{
    if (threadIdx.x < 2) p[threadIdx.x] = 0.0;
}

// ---------------- basis matrices ----------------
// Sf[a,m] = sin(pi*(a-255)*(m+1)/511)        (511 x 510)
// CS  = [C | S]   (510 x 1022), C[p,a]=cos(pi*p*(a-255)/511), S likewise sin
// CS2 = [-S | C]  (510 x 1022)
__global__ void basis_kernel(float* __restrict__ Sf, float* __restrict__ CS, float* __restrict__ CS2)
{
    int idx = blockIdx.x * 256 + threadIdx.x;
    if (idx < 511 * 510) {
        int a = idx / 510, m = idx % 510;
        double k = (double)(a - 255);
        Sf[idx] = (float)sin(PI_D * k * (double)(m + 1) / 511.0);
    }
    if (idx < 510 * 1022) {
        int p = idx / 1022, a = idx % 1022;
        if (a < 511) {
            double k = (double)(a - 255);
            double ang = PI_D * (double)p * k / 511.0;
            CS[idx]  = (float)cos(ang);
            CS2[idx] = (float)(-sin(ang));
        } else {
            double k = (double)(a - 511 - 255);
            double ang = PI_D * (double)p * k / 511.0;
            CS[idx]  = (float)sin(ang);
            CS2[idx] = (float)cos(ang);
        }
    }
}

// ---------------- 5-point stencil A ----------------
__device__ __forceinline__ float computeA(const float* __restrict__ xb,
                                          const void* __restrict__ cb,
                                          int p, int q, int mode)
{
    if (p < 1 || p > 510 || q < 1 || q > 510) return 0.f;
    int i = p - 1, j = q - 1;
    float a   = ldin(cb, (long)i * MM + j, mode);
    float aw  = ldin(cb, (long)i * MM + (j > 0 ? j - 1 : 0), mode);
    float ae  = ldin(cb, (long)i * MM + (j < MM - 1 ? j + 1 : MM - 1), mode);
    float an  = ldin(cb, (long)(i < MM - 1 ? i + 1 : MM - 1) * MM + j, mode);
    float as_ = ldin(cb, (long)(i > 0 ? i - 1 : 0) * MM + j, mode);
    float sw = -2.f * aw  * a / (aw  + a);
    float se = -2.f * ae  * a / (ae  + a);
    float sn = -2.f * an  * a / (an  + a);
    float ss = -2.f * as_ * a / (as_ + a);
    float sc = -(sw + se + sn + ss);
    return ss * xb[(p - 1) * NN + q] + sw * xb[p * NN + q - 1] + sc * xb[p * NN + q]
         + se * xb[p * NN + q + 1] + sn * xb[(p + 1) * NN + q];
}

// one Richardson step: xout = xin + w*(f - A(xin)),  w = 40/512
__global__ void rich_kernel(const float* __restrict__ xin, float* __restrict__ xout,
                            const void* __restrict__ f, const void* __restrict__ coef,
                            int b0, const int* __restrict__ dmode)
{
    int mode = dmode[0];
    int q = blockIdx.x * 32 + threadIdx.x;
    int p = blockIdx.y * 8 + threadIdx.y;
    int bz = blockIdx.z;
    int b = b0 + bz;
    if (p >= NN || q >= NN) return;
    long xo = (long)bz * NN2;
    const char* cc = (const char*)coef + ((long)b * MM2 << (mode + 1));
    const char* fc = (const char*)f + ((long)b * NN2 << (mode + 1));
    float Ax = computeA(xin + xo, cc, p, q, mode);
    float fv = ldin(fc, (long)p * NN + q, mode);
    xout[xo + p * NN + q] = xin[xo + p * NN + q] + 0.078125f * (fv - Ax);
}

__global__ void resid_kernel(const float* __restrict__ x,
                             const void* __restrict__ f, const void* __restrict__ coef,
                             float* __restrict__ r1, int b0, const int* __restrict__ dmode)
{
    int mode = dmode[0];
    int j = blockIdx.x * 32 + threadIdx.x;
    int i = blockIdx.y * 8 + threadIdx.y;
    int bz = blockIdx.z;
    int b = b0 + bz;
    if (i >= MM || j >= MM) return;
    int p = i + 1, q = j + 1;
    const char* cc = (const char*)coef + ((long)b * MM2 << (mode + 1));
    const char* fc = (const char*)f + ((long)b * NN2 << (mode + 1));
    float Ax = computeA(x + (long)bz * NN2, cc, p, q, mode);
    r1[(long)bz * MM2 + i * MM + j] = ldin(fc, (long)p * NN + q, mode) - Ax;
}

__global__ void update_kernel(float* __restrict__ x,
                              const void* __restrict__ coef,
                              const float* __restrict__ F1, const float* __restrict__ F2,
                              int b0, const int* __restrict__ dmode)
{
    int mode = dmode[0];
    int j = blockIdx.x * 32 + threadIdx.x;
    int i = blockIdx.y * 8 + threadIdx.y;
    int bz = blockIdx.z;
    int b = b0 + bz;
    if (i >= MM || j >= MM) return;
    float cf = ldin(coef, (long)b * MM2 + i * MM + j, mode);
    long o = (long)bz * MM2 + i * MM + j;
    float e = (cf < 1.0f) ? (F1[o] / cf) : (F2[o] * cf);
    x[(long)bz * NN2 + (i + 1) * NN + (j + 1)] += e;
}

__global__ void norm_kernel(const float* __restrict__ x,
                            const void* __restrict__ f, const void* __restrict__ coef,
                            double* __restrict__ acc, int b0, const int* __restrict__ dmode)
{
    int mode = dmode[0];
    int q = blockIdx.x * 32 + threadIdx.x;
    int p = blockIdx.y * 8 + threadIdx.y;
    int bz = blockIdx.z;
    int b = b0 + bz;
    double r2 = 0.0, f2 = 0.0;
    if (p < NN && q < NN) {
        const char* cc = (const char*)coef + ((long)b * MM2 << (mode + 1));
        const char* fc = (const char*)f + ((long)b * NN2 << (mode + 1));
        float Ax = computeA(x + (long)bz * NN2, cc, p, q, mode);
        float fv = ldin(fc, (long)p * NN + q, mode);
        float rv = fv - Ax;
        r2 = (double)rv * (double)rv;
        f2 = (double)fv * (double)fv;
    }
    for (int off = 32; off > 0; off >>= 1) {
        r2 += __shfl_down(r2, off, 64);
        f2 += __shfl_down(f2, off, 64);
    }
    __shared__ double sr[4], sf2[4];
    int tid = threadIdx.y * 32 + threadIdx.x;
    int wid = tid >> 6, lane = tid & 63;
    if (lane == 0) { sr[wid] = r2; sf2[wid] = f2; }
    __syncthreads();
    if (tid == 0) {
        atomicAdd(&acc[0], sr[0] + sr[1] + sr[2] + sr[3]);
        atomicAdd(&acc[1], sf2[0] + sf2[1] + sf2[2] + sf2[3]);
    }
}

__global__ void finalize_kernel(const double* __restrict__ acc, float* __restrict__ out)
{
    out[0] = (float)sqrt(acc[0] / acc[1]);
}

// ---------------- tiled complex 3x3 conv ----------------
// Block (64,4) computes a 64x16 output tile for ALL Cout channels.
// Weights staged in LDS once per block (register-cached by unroll).
// normal: eff_w[o,i][dy][dx] = w[b,o,i,dy,dx];  tmode: conj(w[b,i,o,dx,dy])
template<int CIN, int COUT, int HASI>
__global__ __launch_bounds__(256) void cconv_tile(
    const float* __restrict__ in_r, const float* __restrict__ in_i,
    const void* __restrict__ w_r, const void* __restrict__ w_i,
    float* __restrict__ out_r, float* __restrict__ out_i,
    const void* __restrict__ th_r, const void* __restrict__ th_i,
    long in_bs, long out_bs, int tmode, int b0, const int* __restrict__ dmode)
{
    int mode = dmode[0];
    int bz = blockIdx.z;
    int b  = b0 + bz;
    __shared__ float swr[COUT][CIN][9], swi[COUT][CIN][9];
    int tid = threadIdx.y * 64 + threadIdx.x;
    if (tid < COUT * CIN * 9) {
        int o = tid / (CIN * 9), rem = tid % (CIN * 9), i = rem / 9, t = rem % 9;
        int dy = t / 3, dx = t % 3;
        float r, im;
        if (!tmode) {
            long idx = (((long)b * COUT + o) * CIN + i) * 9 + t;
            r = ldin(w_r, idx, mode); im = ldin(w_i, idx, mode);
        } else {
            long idx = (((long)b * CIN + i) * COUT + o) * 9 + dx * 3 + dy;
            r = ldin(w_r, idx, mode); im = -ldin(w_i, idx, mode);
        }
        swr[o][i][t] = r; swi[o][i][t] = im;
    }
    __syncthreads();
    int x  = blockIdx.x * 64 + threadIdx.x;
    int y0 = blockIdx.y * 16 + threadIdx.y * 4;
    if (x >= HW) return;
    float accr[COUT][4] = {}, acci[COUT][4] = {};
    #pragma unroll
    for (int i = 0; i < CIN; ++i) {
        const float* ir = in_r + (long)bz * in_bs + (long)i * HW2;
        const float* ii = HASI ? (in_i + (long)bz * in_bs + (long)i * HW2) : nullptr;
        #pragma unroll
        for (int ry = 0; ry < 6; ++ry) {
            int yy = y0 - 1 + ry;
            bool yok = (yy >= 0 && yy < HW);
            float vr[3], vi[3];
            #pragma unroll
            for (int d = 0; d < 3; ++d) {
                int xx = x - 1 + d;
                bool ok = yok && (xx >= 0) && (xx < HW);
                vr[d] = ok ? ir[(long)yy * HW + xx] : 0.f;
                if (HASI) vi[d] = ok ? ii[(long)yy * HW + xx] : 0.f;
            }
            #pragma unroll
            for (int k = 0; k < 4; ++k) {
                int dy = ry - k;
                if (dy < 0 || dy > 2) continue;
                #pragma unroll
                for (int o = 0; o < COUT; ++o) {
                    #pragma unroll
                    for (int d = 0; d < 3; ++d) {
                        float wr = swr[o][i][dy * 3 + d], wi = swi[o][i][dy * 3 + d];
                        accr[o][k] += vr[d] * wr;
                        acci[o][k] += vr[d] * wi;
                        if (HASI) { accr[o][k] -= vi[d] * wi; acci[o][k] += vi[d] * wr; }
                    }
                }
            }
        }
    }
    #pragma unroll
    for (int o = 0; o < COUT; ++o) {
        #pragma unroll
        for (int k = 0; k < 4; ++k) {
            int yy = y0 + k;
            if (yy >= HW) continue;
            float ar = accr[o][k], ai = acci[o][k];
            if (th_r) {
                float tr = ldin(th_r, (long)b * HW2 + (long)yy * HW + x, mode);
                float ti = ldin(th_i, (long)b * HW2 + (long)yy * HW + x, mode);
                float nr = ar * tr - ai * ti, ni = ar * ti + ai * tr;
                ar = nr; ai = ni;
            }
            long oo = (long)bz * out_bs + (long)o * HW2 + (long)yy * HW + x;
            out_r[oo] = ar;
            out_i[oo] = ai;
        }
    }
}

// ---------------- MFMA GEMM, fp32 via bf16 split-3 ----------------
// C[z] (+)= alpha * A[z] * op(B[z]); row-major; bT => B stored N x K.
// v = hi + lo (bf16 each); A*B ~= Ah*Bh + Ah*Bl + Al*Bh  (rel err ~3e-5)
#define GM 64
#define GN 64
#define GK 32
__global__ __launch_bounds__(256) void gemm_mfma(
    const float* __restrict__ A, const float* __restrict__ B, float* __restrict__ C,
    int M, int N, int K, int lda, int ldb, int ldc,
    long asb, long bsb, long csb, float alpha, int beta, int bT)
{
    int z = blockIdx.z;
    A += (long)z * asb; B += (long)z * bsb; C += (long)z * csb;
    __shared__ short Ah[GM * GK], Al[GM * GK], Bh[GN * GK], Bl[GN * GK];
    int tid = threadIdx.x;
    int wave = tid >> 6, lane = tid & 63;
    int wm = (wave & 1) * 32, wn = (wave >> 1) * 32;
    int lr = lane & 15, lq = lane >> 4;
    int m0 = blockIdx.y * GM, n0 = blockIdx.x * GN;
    float4v acc[2][2] = {};

    for (int k0 = 0; k0 < K; k0 += GK) {
        {   // stage A 64x32: thread -> row m=tid>>2, k-offset (tid&3)*8
            int m = tid >> 2, kk = (tid & 3) * 8;
            int gm = m0 + m;
            const float* ap = A + (long)gm * lda + k0 + kk;
            #pragma unroll
            for (int j = 0; j < 8; ++j) {
                int gk = k0 + kk + j;
                float v = (gm < M && gk < K) ? ap[j] : 0.f;
                short h = f2bf(v);
                Ah[m * GK + kk + j] = h;
                Al[m * GK + kk + j] = f2bf(v - bfs2f(h));
            }
        }
        if (bT) {   // B stored N x K: Bs[n][k] direct
            int n = tid >> 2, kk = (tid & 3) * 8;
            int gn = n0 + n;
            const float* bp = B + (long)gn * ldb + k0 + kk;
            #pragma unroll
            for (int j = 0; j < 8; ++j) {
                int gk = k0 + kk + j;
                float v = (gn < N && gk < K) ? bp[j] : 0.f;
                short h = f2bf(v);
                Bh[n * GK + kk + j] = h;
                Bl[n * GK + kk + j] = f2bf(v - bfs2f(h));
            }
        } else {    // B stored K x N: transpose into Bs[n][k]
            int k = tid >> 3, nn = (tid & 7) * 8;
            int gk = k0 + k;
            const float* bp = B + (long)gk * ldb + n0 + nn;
            #pragma unroll
            for (int j = 0; j < 8; ++j) {
                int gn = n0 + nn + j;
                float v = (gk < K && gn < N) ? bp[j] : 0.f;
                short h = f2bf(v);
                Bh[(nn + j) * GK + k] = h;
                Bl[(nn + j) * GK + k] = f2bf(v - bfs2f(h));
            }
        }
        __syncthreads();
        short8 ah[2], al[2], bh[2], bl[2];
        #pragma unroll
        for (int mt = 0; mt < 2; ++mt) {
            int mloc = wm + mt * 16 + lr;
            ah[mt] = *(const short8*)&Ah[mloc * GK + lq * 8];
            al[mt] = *(const short8*)&Al[mloc * GK + lq * 8];
        }
        #pragma unroll
        for (int nt = 0; nt < 2; ++nt) {
            int nloc = wn + nt * 16 + lr;
            bh[nt] = *(const short8*)&Bh[nloc * GK + lq * 8];
            bl[nt] = *(const short8*)&Bl[nloc * GK + lq * 8];
        }
        #pragma unroll
        for (int mt = 0; mt < 2; ++mt)
            #pragma unroll
            for (int nt = 0; nt < 2; ++nt) {
                acc[mt][nt] = __builtin_amdgcn_mfma_f32_16x16x32_bf16(ah[mt], bh[nt], acc[mt][nt], 0, 0, 0);
                acc[mt][nt] = __builtin_amdgcn_mfma_f32_16x16x32_bf16(ah[mt], bl[nt], acc[mt][nt], 0, 0, 0);
                acc[mt][nt] = __builtin_amdgcn_mfma_f32_16x16x32_bf16(al[mt], bh[nt], acc[mt][nt], 0, 0, 0);
            }
        __syncthreads();
    }
    // D mapping: row = (lane>>4)*4 + r, col = lane&15 (per 16x16 tile)
    #pragma unroll
    for (int mt = 0; mt < 2; ++mt)
        #pragma unroll
        for (int nt = 0; nt < 2; ++nt)
            #pragma unroll
            for (int r = 0; r < 4; ++r) {
                int gm = m0 + wm + mt * 16 + lq * 4 + r;
                int gn = n0 + wn + nt * 16 + lr;
                if (gm < M && gn < N) {
                    float v = alpha * acc[mt][nt][r];
                    if (beta) v += C[(long)gm * ldc + gn];
                    C[(long)gm * ldc + gn] = v;
                }
            }
}

extern "C" void kernel_launch(void* const* d_in, const int* in_sizes, int n_in,
                              void* d_out, int out_size, void* d_ws, size_t ws_size,
                              hipStream_t stream)
{
    const void* f    = d_in[0];
    const void* coef = d_in[1];
    const void* W1r[2] = {d_in[2],  d_in[8]};
    const void* W1i[2] = {d_in[3],  d_in[9]};
    const void* W2r[2] = {d_in[4],  d_in[10]};
    const void* W2i[2] = {d_in[5],  d_in[11]};
    const void* W3r[2] = {d_in[6],  d_in[12]};
    const void* W3i[2] = {d_in[7],  d_in[13]};
    const void* THr[2] = {d_in[14], d_in[16]};
    const void* THi[2] = {d_in[15], d_in[17]};

    sentinel_kernel<<<1, 64, 0, stream>>>((float*)d_out);

    // ---- exact ws accounting; pick largest chunk cb in {8,4,2,1} that fits ----
    const size_t PERSIST = 128 + 260672 + 521280 + 521280;
    const size_t PERB    = 2 * 262144 + 3 * 260160 + 2 * 260672
                         + 261184 + 522304 + 4 * 1044544;
    size_t ws_floats = ws_size / sizeof(float);
    int cb = 8;
    while (cb > 1 && PERSIST + (size_t)cb * PERB > ws_floats) cb >>= 1;

    float* ws = (float*)d_ws;
    size_t off = 0;
    auto alloc = [&](size_t n) { size_t o = off; off += (n + 63) & ~(size_t)63; return ws + o; };
    double* acc  = (double*)alloc(64);
    int*   dmode = (int*)alloc(64);
    float* Sf   = alloc(511L * 510);
    float* CS   = alloc(510L * 1022);
    float* CS2  = alloc(510L * 1022);
    float* xcur = alloc((size_t)cb * NN2);
    float* xnxt = alloc((size_t)cb * NN2);
    float* r1   = alloc((size_t)cb * MM2);
    float* F1c  = alloc((size_t)cb * MM2);
    float* F2c  = alloc((size_t)cb * MM2);
    float* T1   = alloc((size_t)cb * 511 * 510);   // reused as X
    float* Y    = alloc((size_t)cb * 510 * 511);
    float* G    = alloc((size_t)cb * HW2);
    float* outRI= alloc((size_t)cb * 2 * HW2);
    float* bufAr= alloc((size_t)cb * 4 * HW2);
    float* bufAi= alloc((size_t)cb * 4 * HW2);
    float* bufBr= alloc((size_t)cb * 4 * HW2);
    float* bufBi= alloc((size_t)cb * 4 * HW2);
    float* X = T1;

    detect_kernel<<<1, 256, 0, stream>>>(f, dmode);
    zerod_kernel<<<1, 64, 0, stream>>>(acc);
    basis_kernel<<<dim3((510 * 1022 + 255) / 256), 256, 0, stream>>>(Sf, CS, CS2);

    dim3 blk(32, 8);
    dim3 gridc(16, 64, cb);
    dim3 cblk(64, 4);
    dim3 cgrid(8, 32, cb);

    auto gemm = [&](const float* A, const float* B, float* C, int M, int N, int K,
                    int lda, int ldb, int ldc, long asb, long bsb, long csb,
                    float alpha, int beta, int bT) {
        dim3 g((N + GN - 1) / GN, (M + GM - 1) / GM, cb);
        gemm_mfma<<<g, 256, 0, stream>>>(A, B, C, M, N, K, lda, ldb, ldc, asb, bsb, csb, alpha, beta, bT);
    };

    const float cfwd = -4.0f / 1044484.0f;  // -4/1022^2
    long nzero = (long)cb * NN2;

    for (int b0 = 0; b0 < 8; b0 += cb) {
        // x = 0; 10 Richardson iterations (even count => ends in xcur)
        zerof_kernel<<<dim3((nzero + 255) / 256), 256, 0, stream>>>(xcur, nzero);
        float* cur = xcur; float* nxt = xnxt;
        for (int it = 0; it < 10; ++it) {
            rich_kernel<<<gridc, blk, 0, stream>>>(cur, nxt, f, coef, b0, dmode);
            float* t = cur; cur = nxt; nxt = t;
        }
        resid_kernel<<<gridc, blk, 0, stream>>>(xcur, f, coef, r1, b0, dmode);

        // forward sine transform (shared by both _fns_H calls): G = cfwd * Sf * r1 * Sf^T
        gemm(Sf, r1, T1, 511, 510, 510, 510, 510, 510, 0, MM2, 511L * 510, 1.f, 0, 0);
        gemm(T1, Sf, G, 511, 511, 510, 510, 510, 511, 511L * 510, 0, HW2, cfwd, 0, 1);

        for (int t = 0; t < 2; ++t) {
            // chain: G ->(w1)-> bufA ->(w2)-> bufB ->(w3,*theta)-> outRI
            cconv_tile<1, 4, 0><<<cgrid, cblk, 0, stream>>>(
                G, nullptr, W1r[t], W1i[t], bufAr, bufAi, nullptr, nullptr,
                HW2, 4L * HW2, 0, b0, dmode);
            cconv_tile<4, 4, 1><<<cgrid, cblk, 0, stream>>>(
                bufAr, bufAi, W2r[t], W2i[t], bufBr, bufBi, nullptr, nullptr,
                4L * HW2, 4L * HW2, 0, b0, dmode);
            cconv_tile<4, 1, 1><<<cgrid, cblk, 0, stream>>>(
                bufBr, bufBi, W3r[t], W3i[t], outRI, outRI + HW2, THr[t], THi[t],
                4L * HW2, 2L * HW2, 0, b0, dmode);
            // transposed-conj chain
            cconv_tile<1, 4, 1><<<cgrid, cblk, 0, stream>>>(
                outRI, outRI + HW2, W3r[t], W3i[t], bufAr, bufAi, nullptr, nullptr,
                2L * HW2, 4L * HW2, 1, b0, dmode);
            cconv_tile<4, 4, 1><<<cgrid, cblk, 0, stream>>>(
                bufAr, bufAi, W2r[t], W2i[t], bufBr, bufBi, nullptr, nullptr,
                4L * HW2, 4L * HW2, 1, b0, dmode);
            cconv_tile<4, 1, 1><<<cgrid, cblk, 0, stream>>>(
                bufBr, bufBi, W1r[t], W1i[t], outRI, outRI + HW2, nullptr, nullptr,
                4L * HW2, 2L * HW2, 1, b0, dmode);

            // inverse: X=[C|S]*[R;I], Y=[-S|C]*[R;I], F = X*C^T + Y*S^T
            float* Ft = (t == 0) ? F1c : F2c;
            gemm(CS,  outRI, X, 510, 511, 1022, 1022, 511, 511, 0, 2L * HW2, 510L * 511, 1.f, 0, 0);
            gemm(CS2, outRI, Y, 510, 511, 1022, 1022, 511, 511, 0, 2L * HW2, 510L * 511, 1.f, 0, 0);
            gemm(X, CS,       Ft, 510, 510, 511, 511, 1022, 510, 510L * 511, 0, MM2, 1.f, 0, 1);
            gemm(Y, CS + 511, Ft, 510, 510, 511, 511, 1022, 510, 510L * 511, 0, MM2, 1.f, 1, 1);
        }

        update_kernel<<<gridc, blk, 0, stream>>>(xcur, coef, F1c, F2c, b0, dmode);
        norm_kernel<<<gridc, blk, 0, stream>>>(xcur, f, coef, acc, b0, dmode);
    }

    finalize_kernel<<<1, 1, 0, stream>>>(acc, (float*)d_out);
}

// Round 7
// 3357.556 us; speedup vs baseline: 2.6631x; 2.6631x over previous
//
#include <hip/hip_runtime.h>
#include <hip/hip_bf16.h>
#include <math.h>

#define HW   511
#define HW2  261121      // 511*511
#define MM   510
#define MM2  260100      // 510*510
#define NN   512
#define NN2  262144      // 512*512
#define PI_D 3.14159265358979323846

typedef __attribute__((ext_vector_type(8))) short short8;
typedef __attribute__((ext_vector_type(4))) float float4v;

__device__ __forceinline__ float bf2f(const __hip_bfloat16 v) { return __bfloat162float(v); }

// dual-mode input read: mode=0 -> bf16 storage, mode=1 -> float32 storage
__device__ __forceinline__ float ldin(const void* p, long i, int mode)
{
    return mode ? ((const float*)p)[i] : bf2f(((const __hip_bfloat16*)p)[i]);
}

// fp32 -> bf16 (round-to-nearest-even), as raw short
__device__ __forceinline__ short f2bf(float v)
{
    unsigned u = __builtin_bit_cast(unsigned, v);
    u += 0x7FFF + ((u >> 16) & 1);
    return (short)(u >> 16);
}
__device__ __forceinline__ float bfs2f(short s)
{
    unsigned u = ((unsigned)(unsigned short)s) << 16;
    return __builtin_bit_cast(float, u);
}

__global__ void detect_kernel(const void* __restrict__ f, int* __restrict__ mode)
{
    __shared__ int cnt;
    if (threadIdx.x == 0) cnt = 0;
    __syncthreads();
    float v = ((const float*)f)[threadIdx.x];
    float a = fabsf(v);
    int sane = (isfinite(v) && a > 1e-6f && a < 100.f) ? 1 : 0;
    atomicAdd(&cnt, sane);
    __syncthreads();
    if (threadIdx.x == 0) mode[0] = (cnt >= 128) ? 1 : 0;
}

__global__ void sentinel_kernel(float* __restrict__ out) { out[0] = 0.25f; }

__global__ void zerof_kernel(float* __restrict__ p, long n)
{
    long i = (long)blockIdx.x * 256 + threadIdx.x;
    if (i < n) p[i] = 0.f;
}

__global__ void zerod_kernel(double* __restrict__ p)
{
    if (threadIdx.x < 2) p[threadIdx.x] = 0.0;
}

// ---------------- basis matrices ----------------
__global__ void basis_kernel(float* __restrict__ Sf, float* __restrict__ CS, float* __restrict__ CS2)
{
    int idx = blockIdx.x * 256 + threadIdx.x;
    if (idx < 511 * 510) {
        int a = idx / 510, m = idx % 510;
        double k = (double)(a - 255);
        Sf[idx] = (float)sin(PI_D * k * (double)(m + 1) / 511.0);
    }
    if (idx < 510 * 1022) {
        int p = idx / 1022, a = idx % 1022;
        if (a < 511) {
            double k = (double)(a - 255);
            double ang = PI_D * (double)p * k / 511.0;
            CS[idx]  = (float)cos(ang);
            CS2[idx] = (float)(-sin(ang));
        } else {
            double k = (double)(a - 511 - 255);
            double ang = PI_D * (double)p * k / 511.0;
            CS[idx]  = (float)sin(ang);
            CS2[idx] = (float)cos(ang);
        }
    }
}

// ---------------- 5-point stencil A ----------------
__device__ __forceinline__ float computeA(const float* __restrict__ xb,
                                          const void* __restrict__ cb,
                                          int p, int q, int mode)
{
    if (p < 1 || p > 510 || q < 1 || q > 510) return 0.f;
    int i = p - 1, j = q - 1;
    float a   = ldin(cb, (long)i * MM + j, mode);
    float aw  = ldin(cb, (long)i * MM + (j > 0 ? j - 1 : 0), mode);
    float ae  = ldin(cb, (long)i * MM + (j < MM - 1 ? j + 1 : MM - 1), mode);
    float an  = ldin(cb, (long)(i < MM - 1 ? i + 1 : MM - 1) * MM + j, mode);
    float as_ = ldin(cb, (long)(i > 0 ? i - 1 : 0) * MM + j, mode);
    float sw = -2.f * aw  * a / (aw  + a);
    float se = -2.f * ae  * a / (ae  + a);
    float sn = -2.f * an  * a / (an  + a);
    float ss = -2.f * as_ * a / (as_ + a);
    float sc = -(sw + se + sn + ss);
    return ss * xb[(p - 1) * NN + q] + sw * xb[p * NN + q - 1] + sc * xb[p * NN + q]
         + se * xb[p * NN + q + 1] + sn * xb[(p + 1) * NN + q];
}

__global__ void rich_kernel(const float* __restrict__ xin, float* __restrict__ xout,
                            const void* __restrict__ f, const void* __restrict__ coef,
                            int b0, const int* __restrict__ dmode)
{
    int mode = dmode[0];
    int q = blockIdx.x * 32 + threadIdx.x;
    int p = blockIdx.y * 8 + threadIdx.y;
    int bz = blockIdx.z;
    int b = b0 + bz;
    if (p >= NN || q >= NN) return;
    long xo = (long)bz * NN2;
    const char* cc = (const char*)coef + ((long)b * MM2 << (mode + 1));
    const char* fc = (const char*)f + ((long)b * NN2 << (mode + 1));
    float Ax = computeA(xin + xo, cc, p, q, mode);
    float fv = ldin(fc, (long)p * NN + q, mode);
    xout[xo + p * NN + q] = xin[xo + p * NN + q] + 0.078125f * (fv - Ax);
}

__global__ void resid_kernel(const float* __restrict__ x,
                             const void* __restrict__ f, const void* __restrict__ coef,
                             float* __restrict__ r1, int b0, const int* __restrict__ dmode)
{
    int mode = dmode[0];
    int j = blockIdx.x * 32 + threadIdx.x;
    int i = blockIdx.y * 8 + threadIdx.y;
    int bz = blockIdx.z;
    int b = b0 + bz;
    if (i >= MM || j >= MM) return;
    int p = i + 1, q = j + 1;
    const char* cc = (const char*)coef + ((long)b * MM2 << (mode + 1));
    const char* fc = (const char*)f + ((long)b * NN2 << (mode + 1));
    float Ax = computeA(x + (long)bz * NN2, cc, p, q, mode);
    r1[(long)bz * MM2 + i * MM + j] = ldin(fc, (long)p * NN + q, mode) - Ax;
}

__global__ void update_kernel(float* __restrict__ x,
                              const void* __restrict__ coef,
                              const float* __restrict__ F1, const float* __restrict__ F2,
                              int b0, const int* __restrict__ dmode)
{
    int mode = dmode[0];
    int j = blockIdx.x * 32 + threadIdx.x;
    int i = blockIdx.y * 8 + threadIdx.y;
    int bz = blockIdx.z;
    int b = b0 + bz;
    if (i >= MM || j >= MM) return;
    float cf = ldin(coef, (long)b * MM2 + i * MM + j, mode);
    long o = (long)bz * MM2 + i * MM + j;
    float e = (cf < 1.0f) ? (F1[o] / cf) : (F2[o] * cf);
    x[(long)bz * NN2 + (i + 1) * NN + (j + 1)] += e;
}

__global__ void norm_kernel(const float* __restrict__ x,
                            const void* __restrict__ f, const void* __restrict__ coef,
                            double* __restrict__ acc, int b0, const int* __restrict__ dmode)
{
    int mode = dmode[0];
    int q = blockIdx.x * 32 + threadIdx.x;
    int p = blockIdx.y * 8 + threadIdx.y;
    int bz = blockIdx.z;
    int b = b0 + bz;
    double r2 = 0.0, f2 = 0.0;
    if (p < NN && q < NN) {
        const char* cc = (const char*)coef + ((long)b * MM2 << (mode + 1));
        const char* fc = (const char*)f + ((long)b * NN2 << (mode + 1));
        float Ax = computeA(x + (long)bz * NN2, cc, p, q, mode);
        float fv = ldin(fc, (long)p * NN + q, mode);
        float rv = fv - Ax;
        r2 = (double)rv * (double)rv;
        f2 = (double)fv * (double)fv;
    }
    for (int off = 32; off > 0; off >>= 1) {
        r2 += __shfl_down(r2, off, 64);
        f2 += __shfl_down(f2, off, 64);
    }
    __shared__ double sr[4], sf2[4];
    int tid = threadIdx.y * 32 + threadIdx.x;
    int wid = tid >> 6, lane = tid & 63;
    if (lane == 0) { sr[wid] = r2; sf2[wid] = f2; }
    __syncthreads();
    if (tid == 0) {
        atomicAdd(&acc[0], sr[0] + sr[1] + sr[2] + sr[3]);
        atomicAdd(&acc[1], sf2[0] + sf2[1] + sf2[2] + sf2[3]);
    }
}

__global__ void finalize_kernel(const double* __restrict__ acc, float* __restrict__ out)
{
    out[0] = (float)sqrt(acc[0] / acc[1]);
}

// ---------------- complex 3x3 conv, v3 ----------------
// One thread = one pixel, all COUT channels. Weights in LDS (uniform broadcast).
// INK: 0 = real planar, 1 = interleaved float2 (chan stride 2*HW2), 2 = planar complex (in/in2)
// OUTK: 0 = interleaved float2, 1 = planar complex (out/out2), optional theta
// normal: eff_w[o,i][dy][dx] = w[b,o,i,dy,dx];  tmode: conj(w[b,i,o,dx,dy])
template<int CIN, int COUT, int INK, int OUTK>
__global__ __launch_bounds__(256) void cconv2(
    const float* __restrict__ in, const float* __restrict__ in2,
    const void* __restrict__ w_r, const void* __restrict__ w_i,
    float* __restrict__ out, float* __restrict__ out2,
    const void* __restrict__ th_r, const void* __restrict__ th_i,
    long in_bs, long out_bs, int tmode, int b0, const int* __restrict__ dmode)
{
    int mode = dmode[0];
    int bz = blockIdx.z;
    int b  = b0 + bz;
    __shared__ float swr[COUT][CIN][9], swi[COUT][CIN][9];
    int tid = threadIdx.y * 64 + threadIdx.x;
    if (tid < COUT * CIN * 9) {
        int o = tid / (CIN * 9), rem = tid % (CIN * 9), i = rem / 9, t = rem % 9;
        int dy = t / 3, dx = t % 3;
        float r, im;
        if (!tmode) {
            long idx = (((long)b * COUT + o) * CIN + i) * 9 + t;
            r = ldin(w_r, idx, mode); im = ldin(w_i, idx, mode);
        } else {
            long idx = (((long)b * CIN + i) * COUT + o) * 9 + dx * 3 + dy;
            r = ldin(w_r, idx, mode); im = -ldin(w_i, idx, mode);
        }
        swr[o][i][t] = r; swi[o][i][t] = im;
    }
    __syncthreads();
    int x = blockIdx.x * 64 + threadIdx.x;
    int y = blockIdx.y * 4 + threadIdx.y;
    if (x >= HW || y >= HW) return;
    float accr[COUT] = {}, acci[COUT] = {};
    #pragma unroll
    for (int i = 0; i < CIN; ++i) {
        const float*  pr = in  + (long)bz * in_bs + (INK == 1 ? (long)i * 2 * HW2 : (long)i * HW2);
        const float*  pi = (INK == 2) ? (in2 + (long)bz * in_bs + (long)i * HW2) : nullptr;
        #pragma unroll
        for (int dy = 0; dy < 3; ++dy) {
            int yy = y + dy - 1;
            bool yok = (yy >= 0 && yy < HW);
            #pragma unroll
            for (int dx = 0; dx < 3; ++dx) {
                int xx = x + dx - 1;
                bool ok = yok && (xx >= 0) && (xx < HW);
                float vr = 0.f, vi = 0.f;
                if (ok) {
                    if (INK == 0) vr = pr[(long)yy * HW + xx];
                    else if (INK == 1) {
                        float2 v = ((const float2*)pr)[(long)yy * HW + xx];
                        vr = v.x; vi = v.y;
                    } else {
                        vr = pr[(long)yy * HW + xx];
                        vi = pi[(long)yy * HW + xx];
                    }
                }
                int t = dy * 3 + dx;
                #pragma unroll
                for (int o = 0; o < COUT; ++o) {
                    float wr = swr[o][i][t], wi = swi[o][i][t];
                    accr[o] += vr * wr;
                    acci[o] += vr * wi;
                    if (INK != 0) { accr[o] -= vi * wi; acci[o] += vi * wr; }
                }
            }
        }
    }
    #pragma unroll
    for (int o = 0; o < COUT; ++o) {
        float ar = accr[o], ai = acci[o];
        if (th_r) {
            float tr = ldin(th_r, (long)b * HW2 + (long)y * HW + x, mode);
            float ti = ldin(th_i, (long)b * HW2 + (long)y * HW + x, mode);
            float nr = ar * tr - ai * ti, ni = ar * ti + ai * tr;
            ar = nr; ai = ni;
        }
        if (OUTK == 0) {
            float2 v; v.x = ar; v.y = ai;
            ((float2*)(out + (long)bz * out_bs + (long)o * 2 * HW2))[(long)y * HW + x] = v;
        } else {
            long oo = (long)bz * out_bs + (long)o * HW2 + (long)y * HW + x;
            out[oo]  = ar;
            out2[oo] = ai;
        }
    }
}

// ---------------- MFMA GEMM, fp32 via bf16 split-3 ----------------
#define GM 64
#define GN 64
#define GK 32
__global__ __launch_bounds__(256) void gemm_mfma(
    const float* __restrict__ A, const float* __restrict__ B, float* __restrict__ C,
    int M, int N, int K, int lda, int ldb, int ldc,
    long asb, long bsb, long csb, float alpha, int beta, int bT)
{
    int z = blockIdx.z;
    A += (long)z * asb; B += (long)z * bsb; C += (long)z * csb;
    __shared__ short Ah[GM * GK], Al[GM * GK], Bh[GN * GK], Bl[GN * GK];
    int tid = threadIdx.x;
    int wave = tid >> 6, lane = tid & 63;
    int wm = (wave & 1) * 32, wn = (wave >> 1) * 32;
    int lr = lane & 15, lq = lane >> 4;
    int m0 = blockIdx.y * GM, n0 = blockIdx.x * GN;
    float4v acc[2][2] = {};

    for (int k0 = 0; k0 < K; k0 += GK) {
        {
            int m = tid >> 2, kk = (tid & 3) * 8;
            int gm = m0 + m;
            const float* ap = A + (long)gm * lda + k0 + kk;
            #pragma unroll
            for (int j = 0; j < 8; ++j) {
                int gk = k0 + kk + j;
                float v = (gm < M && gk < K) ? ap[j] : 0.f;
                short h = f2bf(v);
                Ah[m * GK + kk + j] = h;
                Al[m * GK + kk + j] = f2bf(v - bfs2f(h));
            }
        }
        if (bT) {
            int n = tid >> 2, kk = (tid & 3) * 8;
            int gn = n0 + n;
            const float* bp = B + (long)gn * ldb + k0 + kk;
            #pragma unroll
            for (int j = 0; j < 8; ++j) {
                int gk = k0 + kk + j;
                float v = (gn < N && gk < K) ? bp[j] : 0.f;
                short h = f2bf(v);
                Bh[n * GK + kk + j] = h;
                Bl[n * GK + kk + j] = f2bf(v - bfs2f(h));
            }
        } else {
            int k = tid >> 3, nn = (tid & 7) * 8;
            int gk = k0 + k;
            const float* bp = B + (long)gk * ldb + n0 + nn;
            #pragma unroll
            for (int j = 0; j < 8; ++j) {
                int gn = n0 + nn + j;
                float v = (gk < K && gn < N) ? bp[j] : 0.f;
                short h = f2bf(v);
                Bh[(nn + j) * GK + k] = h;
                Bl[(nn + j) * GK + k] = f2bf(v - bfs2f(h));
            }
        }
        __syncthreads();
        short8 ah[2], al[2], bh[2], bl[2];
        #pragma unroll
        for (int mt = 0; mt < 2; ++mt) {
            int mloc = wm + mt * 16 + lr;
            ah[mt] = *(const short8*)&Ah[mloc * GK + lq * 8];
            al[mt] = *(const short8*)&Al[mloc * GK + lq * 8];
        }
        #pragma unroll
        for (int nt = 0; nt < 2; ++nt) {
            int nloc = wn + nt * 16 + lr;
            bh[nt] = *(const short8*)&Bh[nloc * GK + lq * 8];
            bl[nt] = *(const short8*)&Bl[nloc * GK + lq * 8];
        }
        #pragma unroll
        for (int mt = 0; mt < 2; ++mt)
            #pragma unroll
            for (int nt = 0; nt < 2; ++nt) {
                acc[mt][nt] = __builtin_amdgcn_mfma_f32_16x16x32_bf16(ah[mt], bh[nt], acc[mt][nt], 0, 0, 0);
                acc[mt][nt] = __builtin_amdgcn_mfma_f32_16x16x32_bf16(ah[mt], bl[nt], acc[mt][nt], 0, 0, 0);
                acc[mt][nt] = __builtin_amdgcn_mfma_f32_16x16x32_bf16(al[mt], bh[nt], acc[mt][nt], 0, 0, 0);
            }
        __syncthreads();
    }
    #pragma unroll
    for (int mt = 0; mt < 2; ++mt)
        #pragma unroll
        for (int nt = 0; nt < 2; ++nt)
            #pragma unroll
            for (int r = 0; r < 4; ++r) {
                int gm = m0 + wm + mt * 16 + lq * 4 + r;
                int gn = n0 + wn + nt * 16 + lr;
                if (gm < M && gn < N) {
                    float v = alpha * acc[mt][nt][r];
                    if (beta) v += C[(long)gm * ldc + gn];
                    C[(long)gm * ldc + gn] = v;
                }
            }
}

extern "C" void kernel_launch(void* const* d_in, const int* in_sizes, int n_in,
                              void* d_out, int out_size, void* d_ws, size_t ws_size,
                              hipStream_t stream)
{
    const void* f    = d_in[0];
    const void* coef = d_in[1];
    const void* W1r[2] = {d_in[2],  d_in[8]};
    const void* W1i[2] = {d_in[3],  d_in[9]};
    const void* W2r[2] = {d_in[4],  d_in[10]};
    const void* W2i[2] = {d_in[5],  d_in[11]};
    const void* W3r[2] = {d_in[6],  d_in[12]};
    const void* W3i[2] = {d_in[7],  d_in[13]};
    const void* THr[2] = {d_in[14], d_in[16]};
    const void* THi[2] = {d_in[15], d_in[17]};

    sentinel_kernel<<<1, 64, 0, stream>>>((float*)d_out);

    // ---- exact ws accounting; pick largest chunk cb in {8,4,2,1} that fits ----
    const size_t PERSIST = 128 + 260672 + 521280 + 521280;
    const size_t PERB    = 2 * 262144 + 3 * 260160 + 2 * 260672
                         + 261184 + 522304 + 2 * 2089152;
    size_t ws_floats = ws_size / sizeof(float);
    int cb = 8;
    while (cb > 1 && PERSIST + (size_t)cb * PERB > ws_floats) cb >>= 1;

    float* ws = (float*)d_ws;
    size_t off = 0;
    auto alloc = [&](size_t n) { size_t o = off; off += (n + 63) & ~(size_t)63; return ws + o; };
    double* acc  = (double*)alloc(64);
    int*   dmode = (int*)alloc(64);
    float* Sf   = alloc(511L * 510);
    float* CS   = alloc(510L * 1022);
    float* CS2  = alloc(510L * 1022);
    float* xcur = alloc((size_t)cb * NN2);
    float* xnxt = alloc((size_t)cb * NN2);
    float* r1   = alloc((size_t)cb * MM2);
    float* F1c  = alloc((size_t)cb * MM2);
    float* F2c  = alloc((size_t)cb * MM2);
    float* T1   = alloc((size_t)cb * 511 * 510);   // reused as X
    float* Y    = alloc((size_t)cb * 510 * 511);
    float* G    = alloc((size_t)cb * HW2);
    float* outRI= alloc((size_t)cb * 2 * HW2);
    float* bufA = alloc((size_t)cb * 8 * HW2);     // interleaved complex, 4 ch
    float* bufB = alloc((size_t)cb * 8 * HW2);
    float* X = T1;

    detect_kernel<<<1, 256, 0, stream>>>(f, dmode);
    zerod_kernel<<<1, 64, 0, stream>>>(acc);
    basis_kernel<<<dim3((510 * 1022 + 255) / 256), 256, 0, stream>>>(Sf, CS, CS2);

    dim3 blk(32, 8);
    dim3 gridc(16, 64, cb);
    dim3 cblk(64, 4);
    dim3 cgrid(8, 128, cb);

    auto gemm = [&](const float* A, const float* B, float* C, int M, int N, int K,
                    int lda, int ldb, int ldc, long asb, long bsb, long csb,
                    float alpha, int beta, int bT) {
        dim3 g((N + GN - 1) / GN, (M + GM - 1) / GM, cb);
        gemm_mfma<<<g, 256, 0, stream>>>(A, B, C, M, N, K, lda, ldb, ldc, asb, bsb, csb, alpha, beta, bT);
    };

    const float cfwd = -4.0f / 1044484.0f;  // -4/1022^2
    long nzero = (long)cb * NN2;

    for (int b0 = 0; b0 < 8; b0 += cb) {
        // x = 0; 10 Richardson iterations (even count => ends in xcur)
        zerof_kernel<<<dim3((nzero + 255) / 256), 256, 0, stream>>>(xcur, nzero);
        float* cur = xcur; float* nxt = xnxt;
        for (int it = 0; it < 10; ++it) {
            rich_kernel<<<gridc, blk, 0, stream>>>(cur, nxt, f, coef, b0, dmode);
            float* t = cur; cur = nxt; nxt = t;
        }
        resid_kernel<<<gridc, blk, 0, stream>>>(xcur, f, coef, r1, b0, dmode);

        // forward sine transform: G = cfwd * Sf * r1 * Sf^T
        gemm(Sf, r1, T1, 511, 510, 510, 510, 510, 510, 0, MM2, 511L * 510, 1.f, 0, 0);
        gemm(T1, Sf, G, 511, 511, 510, 510, 510, 511, 511L * 510, 0, HW2, cfwd, 0, 1);

        for (int t = 0; t < 2; ++t) {
            // forward chain: G(real) -> bufA(int) -> bufB(int) -> outRI(planar,*theta)
            cconv2<1, 4, 0, 0><<<cgrid, cblk, 0, stream>>>(
                G, nullptr, W1r[t], W1i[t], bufA, nullptr, nullptr, nullptr,
                HW2, 8L * HW2, 0, b0, dmode);
            cconv2<4, 4, 1, 0><<<cgrid, cblk, 0, stream>>>(
                bufA, nullptr, W2r[t], W2i[t], bufB, nullptr, nullptr, nullptr,
                8L * HW2, 8L * HW2, 0, b0, dmode);
            cconv2<4, 1, 1, 1><<<cgrid, cblk, 0, stream>>>(
                bufB, nullptr, W3r[t], W3i[t], outRI, outRI + HW2, THr[t], THi[t],
                8L * HW2, 2L * HW2, 0, b0, dmode);
            // transposed-conj chain: outRI(planar) -> bufA(int) -> bufB(int) -> outRI(planar)
            cconv2<1, 4, 2, 0><<<cgrid, cblk, 0, stream>>>(
                outRI, outRI + HW2, W3r[t], W3i[t], bufA, nullptr, nullptr, nullptr,
                2L * HW2, 8L * HW2, 1, b0, dmode);
            cconv2<4, 4, 1, 0><<<cgrid, cblk, 0, stream>>>(
                bufA, nullptr, W2r[t], W2i[t], bufB, nullptr, nullptr, nullptr,
                8L * HW2, 8L * HW2, 1, b0, dmode);
            cconv2<4, 1, 1, 1><<<cgrid, cblk, 0, stream>>>(
                bufB, nullptr, W1r[t], W1i[t], outRI, outRI + HW2, nullptr, nullptr,
                8L * HW2, 2L * HW2, 1, b0, dmode);

            // inverse: X=[C|S]*[R;I], Y=[-S|C]*[R;I], F = X*C^T + Y*S^T
            float* Ft = (t == 0) ? F1c : F2c;
            gemm(CS,  outRI, X, 510, 511, 1022, 1022, 511, 511, 0, 2L * HW2, 510L * 511, 1.f, 0, 0);
            gemm(CS2, outRI, Y, 510, 511, 1022, 1022, 511, 511, 0, 2L * HW2, 510L * 511, 1.f, 0, 0);
            gemm(X, CS,       Ft, 510, 510, 511, 511, 1022, 510, 510L * 511, 0, MM2, 1.f, 0, 1);
            gemm(Y, CS + 511, Ft, 510, 510, 511, 511, 1022, 510, 510L * 511, 0, MM2, 1.f, 1, 1);
        }

        update_kernel<<<gridc, blk, 0, stream>>>(xcur, coef, F1c, F2c, b0, dmode);
        norm_kernel<<<gridc, blk, 0, stream>>>(xcur, f, coef, acc, b0, dmode);
    }

    finalize_kernel<<<1, 1, 0, stream>>>(acc, (float*)d_out);
}

// Round 8
// 1977.430 us; speedup vs baseline: 4.5217x; 1.6979x over previous
//
#include <hip/hip_runtime.h>
#include <hip/hip_bf16.h>
#include <math.h>

#define HW   511
#define HW2  261121      // 511*511
#define MM   510
#define MM2  260100      // 510*510
#define NN   512
#define NN2  262144      // 512*512
#define PI_D 3.14159265358979323846

typedef __attribute__((ext_vector_type(8))) short short8;
typedef __attribute__((ext_vector_type(4))) float float4v;

__device__ __forceinline__ float bf2f(const __hip_bfloat16 v) { return __bfloat162float(v); }

// dual-mode input read: mode=0 -> bf16 storage, mode=1 -> float32 storage
__device__ __forceinline__ float ldin(const void* p, long i, int mode)
{
    return mode ? ((const float*)p)[i] : bf2f(((const __hip_bfloat16*)p)[i]);
}

// fp32 -> bf16 (round-to-nearest-even), as raw short
__device__ __forceinline__ short f2bf(float v)
{
    unsigned u = __builtin_bit_cast(unsigned, v);
    u += 0x7FFF + ((u >> 16) & 1);
    return (short)(u >> 16);
}
__device__ __forceinline__ float bfs2f(short s)
{
    unsigned u = ((unsigned)(unsigned short)s) << 16;
    return __builtin_bit_cast(float, u);
}

__global__ void detect_kernel(const void* __restrict__ f, int* __restrict__ mode)
{
    __shared__ int cnt;
    if (threadIdx.x == 0) cnt = 0;
    __syncthreads();
    float v = ((const float*)f)[threadIdx.x];
    float a = fabsf(v);
    int sane = (isfinite(v) && a > 1e-6f && a < 100.f) ? 1 : 0;
    atomicAdd(&cnt, sane);
    __syncthreads();
    if (threadIdx.x == 0) mode[0] = (cnt >= 128) ? 1 : 0;
}

__global__ void sentinel_kernel(float* __restrict__ out) { out[0] = 0.25f; }

__global__ void zerof_kernel(float* __restrict__ p, long n)
{
    long i = (long)blockIdx.x * 256 + threadIdx.x;
    if (i < n) p[i] = 0.f;
}

__global__ void zerod_kernel(double* __restrict__ p)
{
    if (threadIdx.x < 2) p[threadIdx.x] = 0.0;
}

// ---------------- basis matrices ----------------
__global__ void basis_kernel(float* __restrict__ Sf, float* __restrict__ CS, float* __restrict__ CS2)
{
    int idx = blockIdx.x * 256 + threadIdx.x;
    if (idx < 511 * 510) {
        int a = idx / 510, m = idx % 510;
        double k = (double)(a - 255);
        Sf[idx] = (float)sin(PI_D * k * (double)(m + 1) / 511.0);
    }
    if (idx < 510 * 1022) {
        int p = idx / 1022, a = idx % 1022;
        if (a < 511) {
            double k = (double)(a - 255);
            double ang = PI_D * (double)p * k / 511.0;
            CS[idx]  = (float)cos(ang);
            CS2[idx] = (float)(-sin(ang));
        } else {
            double k = (double)(a - 511 - 255);
            double ang = PI_D * (double)p * k / 511.0;
            CS[idx]  = (float)sin(ang);
            CS2[idx] = (float)cos(ang);
        }
    }
}

// ---------------- 5-point stencil A ----------------
__device__ __forceinline__ float computeA(const float* __restrict__ xb,
                                          const void* __restrict__ cb,
                                          int p, int q, int mode)
{
    if (p < 1 || p > 510 || q < 1 || q > 510) return 0.f;
    int i = p - 1, j = q - 1;
    float a   = ldin(cb, (long)i * MM + j, mode);
    float aw  = ldin(cb, (long)i * MM + (j > 0 ? j - 1 : 0), mode);
    float ae  = ldin(cb, (long)i * MM + (j < MM - 1 ? j + 1 : MM - 1), mode);
    float an  = ldin(cb, (long)(i < MM - 1 ? i + 1 : MM - 1) * MM + j, mode);
    float as_ = ldin(cb, (long)(i > 0 ? i - 1 : 0) * MM + j, mode);
    float sw = -2.f * aw  * a / (aw  + a);
    float se = -2.f * ae  * a / (ae  + a);
    float sn = -2.f * an  * a / (an  + a);
    float ss = -2.f * as_ * a / (as_ + a);
    float sc = -(sw + se + sn + ss);
    return ss * xb[(p - 1) * NN + q] + sw * xb[p * NN + q - 1] + sc * xb[p * NN + q]
         + se * xb[p * NN + q + 1] + sn * xb[(p + 1) * NN + q];
}

__global__ void rich_kernel(const float* __restrict__ xin, float* __restrict__ xout,
                            const void* __restrict__ f, const void* __restrict__ coef,
                            int b0, const int* __restrict__ dmode)
{
    int mode = dmode[0];
    int q = blockIdx.x * 32 + threadIdx.x;
    int p = blockIdx.y * 8 + threadIdx.y;
    int bz = blockIdx.z;
    int b = b0 + bz;
    if (p >= NN || q >= NN) return;
    long xo = (long)bz * NN2;
    const char* cc = (const char*)coef + ((long)b * MM2 << (mode + 1));
    const char* fc = (const char*)f + ((long)b * NN2 << (mode + 1));
    float Ax = computeA(xin + xo, cc, p, q, mode);
    float fv = ldin(fc, (long)p * NN + q, mode);
    xout[xo + p * NN + q] = xin[xo + p * NN + q] + 0.078125f * (fv - Ax);
}

__global__ void resid_kernel(const float* __restrict__ x,
                             const void* __restrict__ f, const void* __restrict__ coef,
                             float* __restrict__ r1, int b0, const int* __restrict__ dmode)
{
    int mode = dmode[0];
    int j = blockIdx.x * 32 + threadIdx.x;
    int i = blockIdx.y * 8 + threadIdx.y;
    int bz = blockIdx.z;
    int b = b0 + bz;
    if (i >= MM || j >= MM) return;
    int p = i + 1, q = j + 1;
    const char* cc = (const char*)coef + ((long)b * MM2 << (mode + 1));
    const char* fc = (const char*)f + ((long)b * NN2 << (mode + 1));
    float Ax = computeA(x + (long)bz * NN2, cc, p, q, mode);
    r1[(long)bz * MM2 + i * MM + j] = ldin(fc, (long)p * NN + q, mode) - Ax;
}

__global__ void update_kernel(float* __restrict__ x,
                              const void* __restrict__ coef,
                              const float* __restrict__ F1, const float* __restrict__ F2,
                              int b0, const int* __restrict__ dmode)
{
    int mode = dmode[0];
    int j = blockIdx.x * 32 + threadIdx.x;
    int i = blockIdx.y * 8 + threadIdx.y;
    int bz = blockIdx.z;
    int b = b0 + bz;
    if (i >= MM || j >= MM) return;
    float cf = ldin(coef, (long)b * MM2 + i * MM + j, mode);
    long o = (long)bz * MM2 + i * MM + j;
    float e = (cf < 1.0f) ? (F1[o] / cf) : (F2[o] * cf);
    x[(long)bz * NN2 + (i + 1) * NN + (j + 1)] += e;
}

__global__ void norm_kernel(const float* __restrict__ x,
                            const void* __restrict__ f, const void* __restrict__ coef,
                            double* __restrict__ acc, int b0, const int* __restrict__ dmode)
{
    int mode = dmode[0];
    int q = blockIdx.x * 32 + threadIdx.x;
    int p = blockIdx.y * 8 + threadIdx.y;
    int bz = blockIdx.z;
    int b = b0 + bz;
    double r2 = 0.0, f2 = 0.0;
    if (p < NN && q < NN) {
        const char* cc = (const char*)coef + ((long)b * MM2 << (mode + 1));
        const char* fc = (const char*)f + ((long)b * NN2 << (mode + 1));
        float Ax = computeA(x + (long)bz * NN2, cc, p, q, mode);
        float fv = ldin(fc, (long)p * NN + q, mode);
        float rv = fv - Ax;
        r2 = (double)rv * (double)rv;
        f2 = (double)fv * (double)fv;
    }
    for (int off = 32; off > 0; off >>= 1) {
        r2 += __shfl_down(r2, off, 64);
        f2 += __shfl_down(f2, off, 64);
    }
    __shared__ double sr[4], sf2[4];
    int tid = threadIdx.y * 32 + threadIdx.x;
    int wid = tid >> 6, lane = tid & 63;
    if (lane == 0) { sr[wid] = r2; sf2[wid] = f2; }
    __syncthreads();
    if (tid == 0) {
        atomicAdd(&acc[0], sr[0] + sr[1] + sr[2] + sr[3]);
        atomicAdd(&acc[1], sf2[0] + sf2[1] + sf2[2] + sf2[3]);
    }
}

__global__ void finalize_kernel(const double* __restrict__ acc, float* __restrict__ out)
{
    out[0] = (float)sqrt(acc[0] / acc[1]);
}

// ---------------- complex 3x3 conv, v4: LDS halo tile, register-lean ----------------
// Block (64,4) -> 64x4 output tile, all COUT channels per thread.
// Per input channel: stage 66x6 float2 halo tile in LDS, then 9 taps from LDS.
// INK: 0 = real planar, 1 = interleaved float2 (chan stride 2*HW2), 2 = planar complex (in/in2)
// OUTK: 0 = interleaved float2, 1 = planar complex (out/out2), optional theta
// normal: eff_w[o,i][dy][dx] = w[b,o,i,dy,dx];  tmode: conj(w[b,i,o,dx,dy])
template<int CIN, int COUT, int INK, int OUTK>
__global__ __launch_bounds__(256, 4) void cconv3(
    const float* __restrict__ in, const float* __restrict__ in2,
    const void* __restrict__ w_r, const void* __restrict__ w_i,
    float* __restrict__ out, float* __restrict__ out2,
    const void* __restrict__ th_r, const void* __restrict__ th_i,
    long in_bs, long out_bs, int tmode, int b0, const int* __restrict__ dmode)
{
    int mode = dmode[0];
    int bz = blockIdx.z;
    int b  = b0 + bz;
    __shared__ float swr[COUT][CIN][9], swi[COUT][CIN][9];
    __shared__ float2 tile[6][66];
    int tid = threadIdx.y * 64 + threadIdx.x;
    if (tid < COUT * CIN * 9) {
        int o = tid / (CIN * 9), rem = tid % (CIN * 9), i = rem / 9, t = rem % 9;
        int dy = t / 3, dx = t % 3;
        float r, im;
        if (!tmode) {
            long idx = (((long)b * COUT + o) * CIN + i) * 9 + t;
            r = ldin(w_r, idx, mode); im = ldin(w_i, idx, mode);
        } else {
            long idx = (((long)b * CIN + i) * COUT + o) * 9 + dx * 3 + dy;
            r = ldin(w_r, idx, mode); im = -ldin(w_i, idx, mode);
        }
        swr[o][i][t] = r; swi[o][i][t] = im;
    }
    int x0 = blockIdx.x * 64, y0 = blockIdx.y * 4;
    int x = x0 + threadIdx.x, y = y0 + threadIdx.y;
    float accr[COUT] = {}, acci[COUT] = {};
    #pragma unroll 1
    for (int i = 0; i < CIN; ++i) {
        __syncthreads();   // WAR guard on tile + (i==0) weight visibility
        const float* pr = in + (long)bz * in_bs + (INK == 1 ? (long)i * 2 * HW2 : (long)i * HW2);
        const float* pi = (INK == 2) ? (in2 + (long)bz * in_bs + (long)i * HW2) : nullptr;
        for (int idx = tid; idx < 66 * 6; idx += 256) {
            int ly = idx / 66, lx = idx % 66;
            int gy = y0 - 1 + ly, gx = x0 - 1 + lx;
            float2 v; v.x = 0.f; v.y = 0.f;
            if (gy >= 0 && gy < HW && gx >= 0 && gx < HW) {
                long gi = (long)gy * HW + gx;
                if (INK == 0) v.x = pr[gi];
                else if (INK == 1) v = ((const float2*)pr)[gi];
                else { v.x = pr[gi]; v.y = pi[gi]; }
            }
            tile[ly][lx] = v;
        }
        __syncthreads();
        #pragma unroll
        for (int dy = 0; dy < 3; ++dy) {
            #pragma unroll
            for (int dx = 0; dx < 3; ++dx) {
                float2 v = tile[threadIdx.y + dy][threadIdx.x + dx];
                int t = dy * 3 + dx;
                #pragma unroll
                for (int o = 0; o < COUT; ++o) {
                    float wr = swr[o][i][t], wi = swi[o][i][t];
                    accr[o] += v.x * wr;
                    acci[o] += v.x * wi;
                    if (INK != 0) { accr[o] -= v.y * wi; acci[o] += v.y * wr; }
                }
            }
        }
    }
    if (x >= HW || y >= HW) return;
    #pragma unroll
    for (int o = 0; o < COUT; ++o) {
        float ar = accr[o], ai = acci[o];
        if (th_r) {
            float tr = ldin(th_r, (long)b * HW2 + (long)y * HW + x, mode);
            float ti = ldin(th_i, (long)b * HW2 + (long)y * HW + x, mode);
            float nr = ar * tr - ai * ti, ni = ar * ti + ai * tr;
            ar = nr; ai = ni;
        }
        if (OUTK == 0) {
            float2 v; v.x = ar; v.y = ai;
            ((float2*)(out + (long)bz * out_bs + (long)o * 2 * HW2))[(long)y * HW + x] = v;
        } else {
            long oo = (long)bz * out_bs + (long)o * HW2 + (long)y * HW + x;
            out[oo]  = ar;
            out2[oo] = ai;
        }
    }
}

// ---------------- MFMA GEMM, fp32 via bf16 split-3 ----------------
#define GM 64
#define GN 64
#define GK 32
__global__ __launch_bounds__(256) void gemm_mfma(
    const float* __restrict__ A, const float* __restrict__ B, float* __restrict__ C,
    int M, int N, int K, int lda, int ldb, int ldc,
    long asb, long bsb, long csb, float alpha, int beta, int bT)
{
    int z = blockIdx.z;
    A += (long)z * asb; B += (long)z * bsb; C += (long)z * csb;
    __shared__ short Ah[GM * GK], Al[GM * GK], Bh[GN * GK], Bl[GN * GK];
    int tid = threadIdx.x;
    int wave = tid >> 6, lane = tid & 63;
    int wm = (wave & 1) * 32, wn = (wave >> 1) * 32;
    int lr = lane & 15, lq = lane >> 4;
    int m0 = blockIdx.y * GM, n0 = blockIdx.x * GN;
    float4v acc[2][2] = {};

    for (int k0 = 0; k0 < K; k0 += GK) {
        {
            int m = tid >> 2, kk = (tid & 3) * 8;
            int gm = m0 + m;
            const float* ap = A + (long)gm * lda + k0 + kk;
            #pragma unroll
            for (int j = 0; j < 8; ++j) {
                int gk = k0 + kk + j;
                float v = (gm < M && gk < K) ? ap[j] : 0.f;
                short h = f2bf(v);
                Ah[m * GK + kk + j] = h;
                Al[m * GK + kk + j] = f2bf(v - bfs2f(h));
            }
        }
        if (bT) {
            int n = tid >> 2, kk = (tid & 3) * 8;
            int gn = n0 + n;
            const float* bp = B + (long)gn * ldb + k0 + kk;
            #pragma unroll
            for (int j = 0; j < 8; ++j) {
                int gk = k0 + kk + j;
                float v = (gn < N && gk < K) ? bp[j] : 0.f;
                short h = f2bf(v);
                Bh[n * GK + kk + j] = h;
                Bl[n * GK + kk + j] = f2bf(v - bfs2f(h));
            }
        } else {
            int k = tid >> 3, nn = (tid & 7) * 8;
            int gk = k0 + k;
            const float* bp = B + (long)gk * ldb + n0 + nn;
            #pragma unroll
            for (int j = 0; j < 8; ++j) {
                int gn = n0 + nn + j;
                float v = (gk < K && gn < N) ? bp[j] : 0.f;
                short h = f2bf(v);
                Bh[(nn + j) * GK + k] = h;
                Bl[(nn + j) * GK + k] = f2bf(v - bfs2f(h));
            }
        }
        __syncthreads();
        short8 ah[2], al[2], bh[2], bl[2];
        #pragma unroll
        for (int mt = 0; mt < 2; ++mt) {
            int mloc = wm + mt * 16 + lr;
            ah[mt] = *(const short8*)&Ah[mloc * GK + lq * 8];
            al[mt] = *(const short8*)&Al[mloc * GK + lq * 8];
        }
        #pragma unroll
        for (int nt = 0; nt < 2; ++nt) {
            int nloc = wn + nt * 16 + lr;
            bh[nt] = *(const short8*)&Bh[nloc * GK + lq * 8];
            bl[nt] = *(const short8*)&Bl[nloc * GK + lq * 8];
        }
        #pragma unroll
        for (int mt = 0; mt < 2; ++mt)
            #pragma unroll
            for (int nt = 0; nt < 2; ++nt) {
                acc[mt][nt] = __builtin_amdgcn_mfma_f32_16x16x32_bf16(ah[mt], bh[nt], acc[mt][nt], 0, 0, 0);
                acc[mt][nt] = __builtin_amdgcn_mfma_f32_16x16x32_bf16(ah[mt], bl[nt], acc[mt][nt], 0, 0, 0);
                acc[mt][nt] = __builtin_amdgcn_mfma_f32_16x16x32_bf16(al[mt], bh[nt], acc[mt][nt], 0, 0, 0);
            }
        __syncthreads();
    }
    #pragma unroll
    for (int mt = 0; mt < 2; ++mt)
        #pragma unroll
        for (int nt = 0; nt < 2; ++nt)
            #pragma unroll
            for (int r = 0; r < 4; ++r) {
                int gm = m0 + wm + mt * 16 + lq * 4 + r;
                int gn = n0 + wn + nt * 16 + lr;
                if (gm < M && gn < N) {
                    float v = alpha * acc[mt][nt][r];
                    if (beta) v += C[(long)gm * ldc + gn];
                    C[(long)gm * ldc + gn] = v;
                }
            }
}

extern "C" void kernel_launch(void* const* d_in, const int* in_sizes, int n_in,
                              void* d_out, int out_size, void* d_ws, size_t ws_size,
                              hipStream_t stream)
{
    const void* f    = d_in[0];
    const void* coef = d_in[1];
    const void* W1r[2] = {d_in[2],  d_in[8]};
    const void* W1i[2] = {d_in[3],  d_in[9]};
    const void* W2r[2] = {d_in[4],  d_in[10]};
    const void* W2i[2] = {d_in[5],  d_in[11]};
    const void* W3r[2] = {d_in[6],  d_in[12]};
    const void* W3i[2] = {d_in[7],  d_in[13]};
    const void* THr[2] = {d_in[14], d_in[16]};
    const void* THi[2] = {d_in[15], d_in[17]};

    sentinel_kernel<<<1, 64, 0, stream>>>((float*)d_out);

    // ---- exact ws accounting; pick largest chunk cb in {8,4,2,1} that fits ----
    const size_t PERSIST = 128 + 260672 + 521280 + 521280;
    const size_t PERB    = 2 * 262144 + 3 * 260160 + 2 * 260672
                         + 261184 + 522304 + 2 * 2089152;
    size_t ws_floats = ws_size / sizeof(float);
    int cb = 8;
    while (cb > 1 && PERSIST + (size_t)cb * PERB > ws_floats) cb >>= 1;

    float* ws = (float*)d_ws;
    size_t off = 0;
    auto alloc = [&](size_t n) { size_t o = off; off += (n + 63) & ~(size_t)63; return ws + o; };
    double* acc  = (double*)alloc(64);
    int*   dmode = (int*)alloc(64);
    float* Sf   = alloc(511L * 510);
    float* CS   = alloc(510L * 1022);
    float* CS2  = alloc(510L * 1022);
    float* xcur = alloc((size_t)cb * NN2);
    float* xnxt = alloc((size_t)cb * NN2);
    float* r1   = alloc((size_t)cb * MM2);
    float* F1c  = alloc((size_t)cb * MM2);
    float* F2c  = alloc((size_t)cb * MM2);
    float* T1   = alloc((size_t)cb * 511 * 510);   // reused as X
    float* Y    = alloc((size_t)cb * 510 * 511);
    float* G    = alloc((size_t)cb * HW2);
    float* outRI= alloc((size_t)cb * 2 * HW2);
    float* bufA = alloc((size_t)cb * 8 * HW2);     // interleaved complex, 4 ch
    float* bufB = alloc((size_t)cb * 8 * HW2);
    float* X = T1;

    detect_kernel<<<1, 256, 0, stream>>>(f, dmode);
    zerod_kernel<<<1, 64, 0, stream>>>(acc);
    basis_kernel<<<dim3((510 * 1022 + 255) / 256), 256, 0, stream>>>(Sf, CS, CS2);

    dim3 blk(32, 8);
    dim3 gridc(16, 64, cb);
    dim3 cblk(64, 4);
    dim3 cgrid(8, 128, cb);

    auto gemm = [&](const float* A, const float* B, float* C, int M, int N, int K,
                    int lda, int ldb, int ldc, long asb, long bsb, long csb,
                    float alpha, int beta, int bT) {
        dim3 g((N + GN - 1) / GN, (M + GM - 1) / GM, cb);
        gemm_mfma<<<g, 256, 0, stream>>>(A, B, C, M, N, K, lda, ldb, ldc, asb, bsb, csb, alpha, beta, bT);
    };

    const float cfwd = -4.0f / 1044484.0f;  // -4/1022^2
    long nzero = (long)cb * NN2;

    for (int b0 = 0; b0 < 8; b0 += cb) {
        // x = 0; 10 Richardson iterations (even count => ends in xcur)
        zerof_kernel<<<dim3((nzero + 255) / 256), 256, 0, stream>>>(xcur, nzero);
        float* cur = xcur; float* nxt = xnxt;
        for (int it = 0; it < 10; ++it) {
            rich_kernel<<<gridc, blk, 0, stream>>>(cur, nxt, f, coef, b0, dmode);
            float* t = cur; cur = nxt; nxt = t;
        }
        resid_kernel<<<gridc, blk, 0, stream>>>(xcur, f, coef, r1, b0, dmode);

        // forward sine transform: G = cfwd * Sf * r1 * Sf^T
        gemm(Sf, r1, T1, 511, 510, 510, 510, 510, 510, 0, MM2, 511L * 510, 1.f, 0, 0);
        gemm(T1, Sf, G, 511, 511, 510, 510, 510, 511, 511L * 510, 0, HW2, cfwd, 0, 1);

        for (int t = 0; t < 2; ++t) {
            // forward chain: G(real) -> bufA(int) -> bufB(int) -> outRI(planar,*theta)
            cconv3<1, 4, 0, 0><<<cgrid, cblk, 0, stream>>>(
                G, nullptr, W1r[t], W1i[t], bufA, nullptr, nullptr, nullptr,
                HW2, 8L * HW2, 0, b0, dmode);
            cconv3<4, 4, 1, 0><<<cgrid, cblk, 0, stream>>>(
                bufA, nullptr, W2r[t], W2i[t], bufB, nullptr, nullptr, nullptr,
                8L * HW2, 8L * HW2, 0, b0, dmode);
            cconv3<4, 1, 1, 1><<<cgrid, cblk, 0, stream>>>(
                bufB, nullptr, W3r[t], W3i[t], outRI, outRI + HW2, THr[t], THi[t],
                8L * HW2, 2L * HW2, 0, b0, dmode);
            // transposed-conj chain: outRI(planar) -> bufA(int) -> bufB(int) -> outRI(planar)
            cconv3<1, 4, 2, 0><<<cgrid, cblk, 0, stream>>>(
                outRI, outRI + HW2, W3r[t], W3i[t], bufA, nullptr, nullptr, nullptr,
                2L * HW2, 8L * HW2, 1, b0, dmode);
            cconv3<4, 4, 1, 0><<<cgrid, cblk, 0, stream>>>(
                bufA, nullptr, W2r[t], W2i[t], bufB, nullptr, nullptr, nullptr,
                8L * HW2, 8L * HW2, 1, b0, dmode);
            cconv3<4, 1, 1, 1><<<cgrid, cblk, 0, stream>>>(
                bufB, nullptr, W1r[t], W1i[t], outRI, outRI + HW2, nullptr, nullptr,
                8L * HW2, 2L * HW2, 1, b0, dmode);

            // inverse: X=[C|S]*[R;I], Y=[-S|C]*[R;I], F = X*C^T + Y*S^T
            float* Ft = (t == 0) ? F1c : F2c;
            gemm(CS,  outRI, X, 510, 511, 1022, 1022, 511, 511, 0, 2L * HW2, 510L * 511, 1.f, 0, 0);
            gemm(CS2, outRI, Y, 510, 511, 1022, 1022, 511, 511, 0, 2L * HW2, 510L * 511, 1.f, 0, 0);
            gemm(X, CS,       Ft, 510, 510, 511, 511, 1022, 510, 510L * 511, 0, MM2, 1.f, 0, 1);
            gemm(Y, CS + 511, Ft, 510, 510, 511, 511, 1022, 510, 510L * 511, 0, MM2, 1.f, 1, 1);
        }

        update_kernel<<<gridc, blk, 0, stream>>>(xcur, coef, F1c, F2c, b0, dmode);
        norm_kernel<<<gridc, blk, 0, stream>>>(xcur, f, coef, acc, b0, dmode);
    }

    finalize_kernel<<<1, 1, 0, stream>>>(acc, (float*)d_out);
}

// Round 9
// 1707.664 us; speedup vs baseline: 5.2360x; 1.1580x over previous
//
#include <hip/hip_runtime.h>
#include <hip/hip_bf16.h>
#include <math.h>

#define HW   511
#define HW2  261121      // 511*511
#define MM   510
#define MM2  260100      // 510*510
#define NN   512
#define NN2  262144      // 512*512
#define PI_D 3.14159265358979323846

typedef __attribute__((ext_vector_type(8))) short short8;
typedef __attribute__((ext_vector_type(4))) float float4v;

__device__ __forceinline__ float bf2f(const __hip_bfloat16 v) { return __bfloat162float(v); }

// dual-mode input read: mode=0 -> bf16 storage, mode=1 -> float32 storage
__device__ __forceinline__ float ldin(const void* p, long i, int mode)
{
    return mode ? ((const float*)p)[i] : bf2f(((const __hip_bfloat16*)p)[i]);
}

// fp32 -> bf16 (round-to-nearest-even), as raw short
__device__ __forceinline__ short f2bf(float v)
{
    unsigned u = __builtin_bit_cast(unsigned, v);
    u += 0x7FFF + ((u >> 16) & 1);
    return (short)(u >> 16);
}
__device__ __forceinline__ float bfs2f(short s)
{
    unsigned u = ((unsigned)(unsigned short)s) << 16;
    return __builtin_bit_cast(float, u);
}

__global__ void detect_kernel(const void* __restrict__ f, int* __restrict__ mode)
{
    __shared__ int cnt;
    if (threadIdx.x == 0) cnt = 0;
    __syncthreads();
    float v = ((const float*)f)[threadIdx.x];
    float a = fabsf(v);
    int sane = (isfinite(v) && a > 1e-6f && a < 100.f) ? 1 : 0;
    atomicAdd(&cnt, sane);
    __syncthreads();
    if (threadIdx.x == 0) mode[0] = (cnt >= 128) ? 1 : 0;
}

__global__ void sentinel_kernel(float* __restrict__ out) { out[0] = 0.25f; }

__global__ void zerod_kernel(double* __restrict__ p)
{
    if (threadIdx.x < 2) p[threadIdx.x] = 0.0;
}

// ---------------- basis matrices ----------------
__global__ void basis_kernel(float* __restrict__ Sf, float* __restrict__ CS, float* __restrict__ CS2)
{
    int idx = blockIdx.x * 256 + threadIdx.x;
    if (idx < 511 * 510) {
        int a = idx / 510, m = idx % 510;
        double k = (double)(a - 255);
        Sf[idx] = (float)sin(PI_D * k * (double)(m + 1) / 511.0);
    }
    if (idx < 510 * 1022) {
        int p = idx / 1022, a = idx % 1022;
        if (a < 511) {
            double k = (double)(a - 255);
            double ang = PI_D * (double)p * k / 511.0;
            CS[idx]  = (float)cos(ang);
            CS2[idx] = (float)(-sin(ang));
        } else {
            double k = (double)(a - 511 - 255);
            double ang = PI_D * (double)p * k / 511.0;
            CS[idx]  = (float)sin(ang);
            CS2[idx] = (float)cos(ang);
        }
    }
}

// ---------------- 5-point stencil A ----------------
__device__ __forceinline__ float computeA(const float* __restrict__ xb,
                                          const void* __restrict__ cb,
                                          int p, int q, int mode)
{
    if (p < 1 || p > 510 || q < 1 || q > 510) return 0.f;
    int i = p - 1, j = q - 1;
    float a   = ldin(cb, (long)i * MM + j, mode);
    float aw  = ldin(cb, (long)i * MM + (j > 0 ? j - 1 : 0), mode);
    float ae  = ldin(cb, (long)i * MM + (j < MM - 1 ? j + 1 : MM - 1), mode);
    float an  = ldin(cb, (long)(i < MM - 1 ? i + 1 : MM - 1) * MM + j, mode);
    float as_ = ldin(cb, (long)(i > 0 ? i - 1 : 0) * MM + j, mode);
    float sw = -2.f * aw  * a / (aw  + a);
    float se = -2.f * ae  * a / (ae  + a);
    float sn = -2.f * an  * a / (an  + a);
    float ss = -2.f * as_ * a / (as_ + a);
    float sc = -(sw + se + sn + ss);
    return ss * xb[(p - 1) * NN + q] + sw * xb[p * NN + q - 1] + sc * xb[p * NN + q]
         + se * xb[p * NN + q + 1] + sn * xb[(p + 1) * NN + q];
}

// x1 = w*f  (first Richardson step from x0=0, no stencil needed)
__global__ void initx_kernel(float* __restrict__ x, const void* __restrict__ f,
                             int b0, const int* __restrict__ dmode)
{
    int mode = dmode[0];
    int q = blockIdx.x * 32 + threadIdx.x;
    int p = blockIdx.y * 8 + threadIdx.y;
    int bz = blockIdx.z;
    int b = b0 + bz;
    if (p >= NN || q >= NN) return;
    const char* fc = (const char*)f + ((long)b * NN2 << (mode + 1));
    x[(long)bz * NN2 + p * NN + q] = 0.078125f * ldin(fc, (long)p * NN + q, mode);
}

__global__ void rich_kernel(const float* __restrict__ xin, float* __restrict__ xout,
                            const void* __restrict__ f, const void* __restrict__ coef,
                            int b0, const int* __restrict__ dmode)
{
    int mode = dmode[0];
    int q = blockIdx.x * 32 + threadIdx.x;
    int p = blockIdx.y * 8 + threadIdx.y;
    int bz = blockIdx.z;
    int b = b0 + bz;
    if (p >= NN || q >= NN) return;
    long xo = (long)bz * NN2;
    const char* cc = (const char*)coef + ((long)b * MM2 << (mode + 1));
    const char* fc = (const char*)f + ((long)b * NN2 << (mode + 1));
    float Ax = computeA(xin + xo, cc, p, q, mode);
    float fv = ldin(fc, (long)p * NN + q, mode);
    xout[xo + p * NN + q] = xin[xo + p * NN + q] + 0.078125f * (fv - Ax);
}

__global__ void resid_kernel(const float* __restrict__ x,
                             const void* __restrict__ f, const void* __restrict__ coef,
                             float* __restrict__ r1, int b0, const int* __restrict__ dmode)
{
    int mode = dmode[0];
    int j = blockIdx.x * 32 + threadIdx.x;
    int i = blockIdx.y * 8 + threadIdx.y;
    int bz = blockIdx.z;
    int b = b0 + bz;
    if (i >= MM || j >= MM) return;
    int p = i + 1, q = j + 1;
    const char* cc = (const char*)coef + ((long)b * MM2 << (mode + 1));
    const char* fc = (const char*)f + ((long)b * NN2 << (mode + 1));
    float Ax = computeA(x + (long)bz * NN2, cc, p, q, mode);
    r1[(long)bz * MM2 + i * MM + j] = ldin(fc, (long)p * NN + q, mode) - Ax;
}

__global__ void update_kernel(float* __restrict__ x,
                              const void* __restrict__ coef,
                              const float* __restrict__ F1, const float* __restrict__ F2,
                              int b0, const int* __restrict__ dmode)
{
    int mode = dmode[0];
    int j = blockIdx.x * 32 + threadIdx.x;
    int i = blockIdx.y * 8 + threadIdx.y;
    int bz = blockIdx.z;
    int b = b0 + bz;
    if (i >= MM || j >= MM) return;
    float cf = ldin(coef, (long)b * MM2 + i * MM + j, mode);
    long o = (long)bz * MM2 + i * MM + j;
    float e = (cf < 1.0f) ? (F1[o] / cf) : (F2[o] * cf);
    x[(long)bz * NN2 + (i + 1) * NN + (j + 1)] += e;
}

// stage 1: per-block partial sums (NO global atomics)
__global__ void norm_kernel(const float* __restrict__ x,
                            const void* __restrict__ f, const void* __restrict__ coef,
                            double* __restrict__ pb, int b0, const int* __restrict__ dmode)
{
    int mode = dmode[0];
    int q = blockIdx.x * 32 + threadIdx.x;
    int p = blockIdx.y * 8 + threadIdx.y;
    int bz = blockIdx.z;
    int b = b0 + bz;
    double r2 = 0.0, f2 = 0.0;
    if (p < NN && q < NN) {
        const char* cc = (const char*)coef + ((long)b * MM2 << (mode + 1));
        const char* fc = (const char*)f + ((long)b * NN2 << (mode + 1));
        float Ax = computeA(x + (long)bz * NN2, cc, p, q, mode);
        float fv = ldin(fc, (long)p * NN + q, mode);
        float rv = fv - Ax;
        r2 = (double)rv * (double)rv;
        f2 = (double)fv * (double)fv;
    }
    for (int off = 32; off > 0; off >>= 1) {
        r2 += __shfl_down(r2, off, 64);
        f2 += __shfl_down(f2, off, 64);
    }
    __shared__ double sr[4], sf2[4];
    int tid = threadIdx.y * 32 + threadIdx.x;
    int wid = tid >> 6, lane = tid & 63;
    if (lane == 0) { sr[wid] = r2; sf2[wid] = f2; }
    __syncthreads();
    if (tid == 0) {
        long blk = ((long)blockIdx.z * gridDim.y + blockIdx.y) * gridDim.x + blockIdx.x;
        pb[2 * blk]     = sr[0] + sr[1] + sr[2] + sr[3];
        pb[2 * blk + 1] = sf2[0] + sf2[1] + sf2[2] + sf2[3];
    }
}

// stage 2: single block folds partials into acc
__global__ void reduce_kernel(const double* __restrict__ pb, long nblk, double* __restrict__ acc)
{
    double r2 = 0.0, f2 = 0.0;
    for (long i = threadIdx.x; i < nblk; i += 256) {
        r2 += pb[2 * i];
        f2 += pb[2 * i + 1];
    }
    for (int off = 32; off > 0; off >>= 1) {
        r2 += __shfl_down(r2, off, 64);
        f2 += __shfl_down(f2, off, 64);
    }
    __shared__ double sr[4], sf2[4];
    int wid = threadIdx.x >> 6, lane = threadIdx.x & 63;
    if (lane == 0) { sr[wid] = r2; sf2[wid] = f2; }
    __syncthreads();
    if (threadIdx.x == 0) {
        acc[0] += sr[0] + sr[1] + sr[2] + sr[3];
        acc[1] += sf2[0] + sf2[1] + sf2[2] + sf2[3];
    }
}

__global__ void finalize_kernel(const double* __restrict__ acc, float* __restrict__ out)
{
    out[0] = (float)sqrt(acc[0] / acc[1]);
}

// ---------------- complex 3x3 conv, LDS halo tile ----------------
template<int CIN, int COUT, int INK, int OUTK>
__global__ __launch_bounds__(256, 4) void cconv3(
    const float* __restrict__ in, const float* __restrict__ in2,
    const void* __restrict__ w_r, const void* __restrict__ w_i,
    float* __restrict__ out, float* __restrict__ out2,
    const void* __restrict__ th_r, const void* __restrict__ th_i,
    long in_bs, long out_bs, int tmode, int b0, const int* __restrict__ dmode)
{
    int mode = dmode[0];
    int bz = blockIdx.z;
    int b  = b0 + bz;
    __shared__ float swr[COUT][CIN][9], swi[COUT][CIN][9];
    __shared__ float2 tile[6][66];
    int tid = threadIdx.y * 64 + threadIdx.x;
    if (tid < COUT * CIN * 9) {
        int o = tid / (CIN * 9), rem = tid % (CIN * 9), i = rem / 9, t = rem % 9;
        int dy = t / 3, dx = t % 3;
        float r, im;
        if (!tmode) {
            long idx = (((long)b * COUT + o) * CIN + i) * 9 + t;
            r = ldin(w_r, idx, mode); im = ldin(w_i, idx, mode);
        } else {
            long idx = (((long)b * CIN + i) * COUT + o) * 9 + dx * 3 + dy;
            r = ldin(w_r, idx, mode); im = -ldin(w_i, idx, mode);
        }
        swr[o][i][t] = r; swi[o][i][t] = im;
    }
    int x0 = blockIdx.x * 64, y0 = blockIdx.y * 4;
    int x = x0 + threadIdx.x, y = y0 + threadIdx.y;
    float accr[COUT] = {}, acci[COUT] = {};
    #pragma unroll 1
    for (int i = 0; i < CIN; ++i) {
        __syncthreads();
        const float* pr = in + (long)bz * in_bs + (INK == 1 ? (long)i * 2 * HW2 : (long)i * HW2);
        const float* pi = (INK == 2) ? (in2 + (long)bz * in_bs + (long)i * HW2) : nullptr;
        for (int idx = tid; idx < 66 * 6; idx += 256) {
            int ly = idx / 66, lx = idx % 66;
            int gy = y0 - 1 + ly, gx = x0 - 1 + lx;
            float2 v; v.x = 0.f; v.y = 0.f;
            if (gy >= 0 && gy < HW && gx >= 0 && gx < HW) {
                long gi = (long)gy * HW + gx;
                if (INK == 0) v.x = pr[gi];
                else if (INK == 1) v = ((const float2*)pr)[gi];
                else { v.x = pr[gi]; v.y = pi[gi]; }
            }
            tile[ly][lx] = v;
        }
        __syncthreads();
        #pragma unroll
        for (int dy = 0; dy < 3; ++dy) {
            #pragma unroll
            for (int dx = 0; dx < 3; ++dx) {
                float2 v = tile[threadIdx.y + dy][threadIdx.x + dx];
                int t = dy * 3 + dx;
                #pragma unroll
                for (int o = 0; o < COUT; ++o) {
                    float wr = swr[o][i][t], wi = swi[o][i][t];
                    accr[o] += v.x * wr;
                    acci[o] += v.x * wi;
                    if (INK != 0) { accr[o] -= v.y * wi; acci[o] += v.y * wr; }
                }
            }
        }
    }
    if (x >= HW || y >= HW) return;
    #pragma unroll
    for (int o = 0; o < COUT; ++o) {
        float ar = accr[o], ai = acci[o];
        if (th_r) {
            float tr = ldin(th_r, (long)b * HW2 + (long)y * HW + x, mode);
            float ti = ldin(th_i, (long)b * HW2 + (long)y * HW + x, mode);
            float nr = ar * tr - ai * ti, ni = ar * ti + ai * tr;
            ar = nr; ai = ni;
        }
        if (OUTK == 0) {
            float2 v; v.x = ar; v.y = ai;
            ((float2*)(out + (long)bz * out_bs + (long)o * 2 * HW2))[(long)y * HW + x] = v;
        } else {
            long oo = (long)bz * out_bs + (long)o * HW2 + (long)y * HW + x;
            out[oo]  = ar;
            out2[oo] = ai;
        }
    }
}

// ---------------- MFMA GEMM, fp32 via bf16 split-3 ----------------
#define GM 64
#define GN 64
#define GK 32
__global__ __launch_bounds__(256) void gemm_mfma(
    const float* __restrict__ A, const float* __restrict__ B, float* __restrict__ C,
    int M, int N, int K, int lda, int ldb, int ldc,
    long asb, long bsb, long csb, float alpha, int beta, int bT)
{
    int z = blockIdx.z;
    A += (long)z * asb; B += (long)z * bsb; C += (long)z * csb;
    __shared__ short Ah[GM * GK], Al[GM * GK], Bh[GN * GK], Bl[GN * GK];
    int tid = threadIdx.x;
    int wave = tid >> 6, lane = tid & 63;
    int wm = (wave & 1) * 32, wn = (wave >> 1) * 32;
    int lr = lane & 15, lq = lane >> 4;
    int m0 = blockIdx.y * GM, n0 = blockIdx.x * GN;
    float4v acc[2][2] = {};

    for (int k0 = 0; k0 < K; k0 += GK) {
        {
            int m = tid >> 2, kk = (tid & 3) * 8;
            int gm = m0 + m;
            const float* ap = A + (long)gm * lda + k0 + kk;
            #pragma unroll
            for (int j = 0; j < 8; ++j) {
                int gk = k0 + kk + j;
                float v = (gm < M && gk < K) ? ap[j] : 0.f;
                short h = f2bf(v);
                Ah[m * GK + kk + j] = h;
                Al[m * GK + kk + j] = f2bf(v - bfs2f(h));
            }
        }
        if (bT) {
            int n = tid >> 2, kk = (tid & 3) * 8;
            int gn = n0 + n;
            const float* bp = B + (long)gn * ldb + k0 + kk;
            #pragma unroll
            for (int j = 0; j < 8; ++j) {
                int gk = k0 + kk + j;
                float v = (gn < N && gk < K) ? bp[j] : 0.f;
                short h = f2bf(v);
                Bh[n * GK + kk + j] = h;
                Bl[n * GK + kk + j] = f2bf(v - bfs2f(h));
            }
        } else {
            int k = tid >> 3, nn = (tid & 7) * 8;
            int gk = k0 + k;
            const float* bp = B + (long)gk * ldb + n0 + nn;
            #pragma unroll
            for (int j = 0; j < 8; ++j) {
                int gn = n0 + nn + j;
                float v = (gk < K && gn < N) ? bp[j] : 0.f;
                short h = f2bf(v);
                Bh[(nn + j) * GK + k] = h;
                Bl[(nn + j) * GK + k] = f2bf(v - bfs2f(h));
            }
        }
        __syncthreads();
        short8 ah[2], al[2], bh[2], bl[2];
        #pragma unroll
        for (int mt = 0; mt < 2; ++mt) {
            int mloc = wm + mt * 16 + lr;
            ah[mt] = *(const short8*)&Ah[mloc * GK + lq * 8];
            al[mt] = *(const short8*)&Al[mloc * GK + lq * 8];
        }
        #pragma unroll
        for (int nt = 0; nt < 2; ++nt) {
            int nloc = wn + nt * 16 + lr;
            bh[nt] = *(const short8*)&Bh[nloc * GK + lq * 8];
            bl[nt] = *(const short8*)&Bl[nloc * GK + lq * 8];
        }
        #pragma unroll
        for (int mt = 0; mt < 2; ++mt)
            #pragma unroll
            for (int nt = 0; nt < 2; ++nt) {
                acc[mt][nt] = __builtin_amdgcn_mfma_f32_16x16x32_bf16(ah[mt], bh[nt], acc[mt][nt], 0, 0, 0);
                acc[mt][nt] = __builtin_amdgcn_mfma_f32_16x16x32_bf16(ah[mt], bl[nt], acc[mt][nt], 0, 0, 0);
                acc[mt][nt] = __builtin_amdgcn_mfma_f32_16x16x32_bf16(al[mt], bh[nt], acc[mt][nt], 0, 0, 0);
            }
        __syncthreads();
    }
    #pragma unroll
    for (int mt = 0; mt < 2; ++mt)
        #pragma unroll
        for (int nt = 0; nt < 2; ++nt)
            #pragma unroll
            for (int r = 0; r < 4; ++r) {
                int gm = m0 + wm + mt * 16 + lq * 4 + r;
                int gn = n0 + wn + nt * 16 + lr;
                if (gm < M && gn < N) {
                    float v = alpha * acc[mt][nt][r];
                    if (beta) v += C[(long)gm * ldc + gn];
                    C[(long)gm * ldc + gn] = v;
                }
            }
}

extern "C" void kernel_launch(void* const* d_in, const int* in_sizes, int n_in,
                              void* d_out, int out_size, void* d_ws, size_t ws_size,
                              hipStream_t stream)
{
    const void* f    = d_in[0];
    const void* coef = d_in[1];
    const void* W1r[2] = {d_in[2],  d_in[8]};
    const void* W1i[2] = {d_in[3],  d_in[9]};
    const void* W2r[2] = {d_in[4],  d_in[10]};
    const void* W2i[2] = {d_in[5],  d_in[11]};
    const void* W3r[2] = {d_in[6],  d_in[12]};
    const void* W3i[2] = {d_in[7],  d_in[13]};
    const void* THr[2] = {d_in[14], d_in[16]};
    const void* THi[2] = {d_in[15], d_in[17]};

    sentinel_kernel<<<1, 64, 0, stream>>>((float*)d_out);

    // ---- exact ws accounting; pick largest chunk cb in {8,4,2,1} that fits ----
    const size_t PERSIST = 128 + 32768 + 260672 + 521280 + 521280;  // acc+mode, pb, Sf, CS, CS2
    const size_t PERB    = 2 * 262144 + 3 * 260160 + 260672 + 521280
                         + 261184 + 522304 + 2 * 2089152;           // x2, r1/F1/F2, T1, XY, G, outRI, bufA/B
    size_t ws_floats = ws_size / sizeof(float);
    int cb = 8;
    while (cb > 1 && PERSIST + (size_t)cb * PERB > ws_floats) cb >>= 1;

    float* ws = (float*)d_ws;
    size_t off = 0;
    auto alloc = [&](size_t n) { size_t o = off; off += (n + 63) & ~(size_t)63; return ws + o; };
    double* acc  = (double*)alloc(64);
    int*   dmode = (int*)alloc(64);
    double* pb   = (double*)alloc(32768);          // 16384 doubles of partials
    float* Sf   = alloc(511L * 510);
    float* CS   = alloc(510L * 1022);
    float* CS2  = alloc(510L * 1022);
    float* xcur = alloc((size_t)cb * NN2);
    float* xnxt = alloc((size_t)cb * NN2);
    float* r1   = alloc((size_t)cb * MM2);
    float* F1c  = alloc((size_t)cb * MM2);
    float* F2c  = alloc((size_t)cb * MM2);
    float* T1   = alloc((size_t)cb * 511 * 510);
    float* XY   = alloc((size_t)cb * 510 * 1022);  // [X | Y] per image, ld=1022
    float* G    = alloc((size_t)cb * HW2);
    float* outRI= alloc((size_t)cb * 2 * HW2);
    float* bufA = alloc((size_t)cb * 8 * HW2);
    float* bufB = alloc((size_t)cb * 8 * HW2);

    detect_kernel<<<1, 256, 0, stream>>>(f, dmode);
    zerod_kernel<<<1, 64, 0, stream>>>(acc);
    basis_kernel<<<dim3((510 * 1022 + 255) / 256), 256, 0, stream>>>(Sf, CS, CS2);

    dim3 blk(32, 8);
    dim3 gridc(16, 64, cb);
    dim3 cblk(64, 4);
    dim3 cgrid(8, 128, cb);

    auto gemm = [&](const float* A, const float* B, float* C, int M, int N, int K,
                    int lda, int ldb, int ldc, long asb, long bsb, long csb,
                    float alpha, int beta, int bT) {
        dim3 g((N + GN - 1) / GN, (M + GM - 1) / GM, cb);
        gemm_mfma<<<g, 256, 0, stream>>>(A, B, C, M, N, K, lda, ldb, ldc, asb, bsb, csb, alpha, beta, bT);
    };

    const float cfwd = -4.0f / 1044484.0f;  // -4/1022^2

    for (int b0 = 0; b0 < 8; b0 += cb) {
        // x1 = w*f, then 9 more Richardson iterations (10 total)
        initx_kernel<<<gridc, blk, 0, stream>>>(xcur, f, b0, dmode);
        float* cur = xcur; float* nxt = xnxt;
        for (int it = 0; it < 9; ++it) {
            rich_kernel<<<gridc, blk, 0, stream>>>(cur, nxt, f, coef, b0, dmode);
            float* t = cur; cur = nxt; nxt = t;
        }
        resid_kernel<<<gridc, blk, 0, stream>>>(cur, f, coef, r1, b0, dmode);

        // forward sine transform: G = cfwd * Sf * r1 * Sf^T
        gemm(Sf, r1, T1, 511, 510, 510, 510, 510, 510, 0, MM2, 511L * 510, 1.f, 0, 0);
        gemm(T1, Sf, G, 511, 511, 510, 510, 510, 511, 511L * 510, 0, HW2, cfwd, 0, 1);

        for (int t = 0; t < 2; ++t) {
            // forward chain: G(real) -> bufA(int) -> bufB(int) -> outRI(planar,*theta)
            cconv3<1, 4, 0, 0><<<cgrid, cblk, 0, stream>>>(
                G, nullptr, W1r[t], W1i[t], bufA, nullptr, nullptr, nullptr,
                HW2, 8L * HW2, 0, b0, dmode);
            cconv3<4, 4, 1, 0><<<cgrid, cblk, 0, stream>>>(
                bufA, nullptr, W2r[t], W2i[t], bufB, nullptr, nullptr, nullptr,
                8L * HW2, 8L * HW2, 0, b0, dmode);
            cconv3<4, 1, 1, 1><<<cgrid, cblk, 0, stream>>>(
                bufB, nullptr, W3r[t], W3i[t], outRI, outRI + HW2, THr[t], THi[t],
                8L * HW2, 2L * HW2, 0, b0, dmode);
            // transposed-conj chain
            cconv3<1, 4, 2, 0><<<cgrid, cblk, 0, stream>>>(
                outRI, outRI + HW2, W3r[t], W3i[t], bufA, nullptr, nullptr, nullptr,
                2L * HW2, 8L * HW2, 1, b0, dmode);
            cconv3<4, 4, 1, 0><<<cgrid, cblk, 0, stream>>>(
                bufA, nullptr, W2r[t], W2i[t], bufB, nullptr, nullptr, nullptr,
                8L * HW2, 8L * HW2, 1, b0, dmode);
            cconv3<4, 1, 1, 1><<<cgrid, cblk, 0, stream>>>(
                bufB, nullptr, W1r[t], W1i[t], outRI, outRI + HW2, nullptr, nullptr,
                8L * HW2, 2L * HW2, 1, b0, dmode);

            // inverse: X = CS*[R;I] (cols 0..510), Y = CS2*[R;I] (cols 511..1021), F = [X|Y]*CS^T
            float* Ft = (t == 0) ? F1c : F2c;
            gemm(CS,  outRI, XY,       510, 511, 1022, 1022, 511, 1022, 0, 2L * HW2, 510L * 1022, 1.f, 0, 0);
            gemm(CS2, outRI, XY + 511, 510, 511, 1022, 1022, 511, 1022, 0, 2L * HW2, 510L * 1022, 1.f, 0, 0);
            gemm(XY, CS, Ft, 510, 510, 1022, 1022, 1022, 510, 510L * 1022, 0, MM2, 1.f, 0, 1);
        }

        update_kernel<<<gridc, blk, 0, stream>>>(cur, coef, F1c, F2c, b0, dmode);
        norm_kernel<<<gridc, blk, 0, stream>>>(cur, f, coef, pb, b0, dmode);
        reduce_kernel<<<1, 256, 0, stream>>>(pb, (long)1024 * cb, acc);
    }

    finalize_kernel<<<1, 1, 0, stream>>>(acc, (float*)d_out);
}

// Round 10
// 1444.347 us; speedup vs baseline: 6.1906x; 1.1823x over previous
//
#include <hip/hip_runtime.h>
#include <hip/hip_bf16.h>
#include <math.h>

#define HW   511
#define HW2  261121      // 511*511
#define MM   510
#define MM2  260100      // 510*510
#define NN   512
#define NN2  262144      // 512*512
#define PI_D 3.14159265358979323846

typedef __attribute__((ext_vector_type(8))) short short8;
typedef __attribute__((ext_vector_type(4))) float float4v;

__device__ __forceinline__ float bf2f(const __hip_bfloat16 v) { return __bfloat162float(v); }

// dual-mode input read: mode=0 -> bf16 storage, mode=1 -> float32 storage
__device__ __forceinline__ float ldin(const void* p, long i, int mode)
{
    return mode ? ((const float*)p)[i] : bf2f(((const __hip_bfloat16*)p)[i]);
}

// fp32 -> bf16 (round-to-nearest-even), as raw short
__device__ __forceinline__ short f2bf(float v)
{
    unsigned u = __builtin_bit_cast(unsigned, v);
    u += 0x7FFF + ((u >> 16) & 1);
    return (short)(u >> 16);
}
__device__ __forceinline__ float bfs2f(short s)
{
    unsigned u = ((unsigned)(unsigned short)s) << 16;
    return __builtin_bit_cast(float, u);
}

__global__ void detect_kernel(const void* __restrict__ f, int* __restrict__ mode)
{
    __shared__ int cnt;
    if (threadIdx.x == 0) cnt = 0;
    __syncthreads();
    float v = ((const float*)f)[threadIdx.x];
    float a = fabsf(v);
    int sane = (isfinite(v) && a > 1e-6f && a < 100.f) ? 1 : 0;
    atomicAdd(&cnt, sane);
    __syncthreads();
    if (threadIdx.x == 0) mode[0] = (cnt >= 128) ? 1 : 0;
}

__global__ void sentinel_kernel(float* __restrict__ out) { out[0] = 0.25f; }

__global__ void zerod_kernel(double* __restrict__ p)
{
    if (threadIdx.x < 2) p[threadIdx.x] = 0.0;
}

// ---------------- basis matrices ----------------
__global__ void basis_kernel(float* __restrict__ Sf, float* __restrict__ CS, float* __restrict__ CS2)
{
    int idx = blockIdx.x * 256 + threadIdx.x;
    if (idx < 511 * 510) {
        int a = idx / 510, m = idx % 510;
        double k = (double)(a - 255);
        Sf[idx] = (float)sin(PI_D * k * (double)(m + 1) / 511.0);
    }
    if (idx < 510 * 1022) {
        int p = idx / 1022, a = idx % 1022;
        if (a < 511) {
            double k = (double)(a - 255);
            double ang = PI_D * (double)p * k / 511.0;
            CS[idx]  = (float)cos(ang);
            CS2[idx] = (float)(-sin(ang));
        } else {
            double k = (double)(a - 511 - 255);
            double ang = PI_D * (double)p * k / 511.0;
            CS[idx]  = (float)sin(ang);
            CS2[idx] = (float)cos(ang);
        }
    }
}

// ---------------- 5-point stencil A ----------------
__device__ __forceinline__ float computeA(const float* __restrict__ xb,
                                          const void* __restrict__ cb,
                                          int p, int q, int mode)
{
    if (p < 1 || p > 510 || q < 1 || q > 510) return 0.f;
    int i = p - 1, j = q - 1;
    float a   = ldin(cb, (long)i * MM + j, mode);
    float aw  = ldin(cb, (long)i * MM + (j > 0 ? j - 1 : 0), mode);
    float ae  = ldin(cb, (long)i * MM + (j < MM - 1 ? j + 1 : MM - 1), mode);
    float an  = ldin(cb, (long)(i < MM - 1 ? i + 1 : MM - 1) * MM + j, mode);
    float as_ = ldin(cb, (long)(i > 0 ? i - 1 : 0) * MM + j, mode);
    float sw = -2.f * aw  * a / (aw  + a);
    float se = -2.f * ae  * a / (ae  + a);
    float sn = -2.f * an  * a / (an  + a);
    float ss = -2.f * as_ * a / (as_ + a);
    float sc = -(sw + se + sn + ss);
    return ss * xb[(p - 1) * NN + q] + sw * xb[p * NN + q - 1] + sc * xb[p * NN + q]
         + se * xb[p * NN + q + 1] + sn * xb[(p + 1) * NN + q];
}

// x1 = w*f  (first Richardson step from x0=0)
__global__ void initx_kernel(float* __restrict__ x, const void* __restrict__ f,
                             int b0, const int* __restrict__ dmode)
{
    int mode = dmode[0];
    int q = blockIdx.x * 32 + threadIdx.x;
    int p = blockIdx.y * 8 + threadIdx.y;
    int bz = blockIdx.z;
    int b = b0 + bz;
    if (p >= NN || q >= NN) return;
    const char* fc = (const char*)f + ((long)b * NN2 << (mode + 1));
    x[(long)bz * NN2 + p * NN + q] = 0.078125f * ldin(fc, (long)p * NN + q, mode);
}

__global__ void rich_kernel(const float* __restrict__ xin, float* __restrict__ xout,
                            const void* __restrict__ f, const void* __restrict__ coef,
                            int b0, const int* __restrict__ dmode)
{
    int mode = dmode[0];
    int q = blockIdx.x * 32 + threadIdx.x;
    int p = blockIdx.y * 8 + threadIdx.y;
    int bz = blockIdx.z;
    int b = b0 + bz;
    if (p >= NN || q >= NN) return;
    long xo = (long)bz * NN2;
    const char* cc = (const char*)coef + ((long)b * MM2 << (mode + 1));
    const char* fc = (const char*)f + ((long)b * NN2 << (mode + 1));
    float Ax = computeA(xin + xo, cc, p, q, mode);
    float fv = ldin(fc, (long)p * NN + q, mode);
    xout[xo + p * NN + q] = xin[xo + p * NN + q] + 0.078125f * (fv - Ax);
}

__global__ void resid_kernel(const float* __restrict__ x,
                             const void* __restrict__ f, const void* __restrict__ coef,
                             float* __restrict__ r1, int b0, const int* __restrict__ dmode)
{
    int mode = dmode[0];
    int j = blockIdx.x * 32 + threadIdx.x;
    int i = blockIdx.y * 8 + threadIdx.y;
    int bz = blockIdx.z;
    int b = b0 + bz;
    if (i >= MM || j >= MM) return;
    int p = i + 1, q = j + 1;
    const char* cc = (const char*)coef + ((long)b * MM2 << (mode + 1));
    const char* fc = (const char*)f + ((long)b * NN2 << (mode + 1));
    float Ax = computeA(x + (long)bz * NN2, cc, p, q, mode);
    r1[(long)bz * MM2 + i * MM + j] = ldin(fc, (long)p * NN + q, mode) - Ax;
}

__global__ void update_kernel(float* __restrict__ x,
                              const void* __restrict__ coef,
                              const float* __restrict__ F1, const float* __restrict__ F2,
                              int b0, const int* __restrict__ dmode)
{
    int mode = dmode[0];
    int j = blockIdx.x * 32 + threadIdx.x;
    int i = blockIdx.y * 8 + threadIdx.y;
    int bz = blockIdx.z;
    int b = b0 + bz;
    if (i >= MM || j >= MM) return;
    float cf = ldin(coef, (long)b * MM2 + i * MM + j, mode);
    long o = (long)bz * MM2 + i * MM + j;
    float e = (cf < 1.0f) ? (F1[o] / cf) : (F2[o] * cf);
    x[(long)bz * NN2 + (i + 1) * NN + (j + 1)] += e;
}

// stage 1: per-block partial sums (NO global atomics)
__global__ void norm_kernel(const float* __restrict__ x,
                            const void* __restrict__ f, const void* __restrict__ coef,
                            double* __restrict__ pb, int b0, const int* __restrict__ dmode)
{
    int mode = dmode[0];
    int q = blockIdx.x * 32 + threadIdx.x;
    int p = blockIdx.y * 8 + threadIdx.y;
    int bz = blockIdx.z;
    int b = b0 + bz;
    double r2 = 0.0, f2 = 0.0;
    if (p < NN && q < NN) {
        const char* cc = (const char*)coef + ((long)b * MM2 << (mode + 1));
        const char* fc = (const char*)f + ((long)b * NN2 << (mode + 1));
        float Ax = computeA(x + (long)bz * NN2, cc, p, q, mode);
        float fv = ldin(fc, (long)p * NN + q, mode);
        float rv = fv - Ax;
        r2 = (double)rv * (double)rv;
        f2 = (double)fv * (double)fv;
    }
    for (int off = 32; off > 0; off >>= 1) {
        r2 += __shfl_down(r2, off, 64);
        f2 += __shfl_down(f2, off, 64);
    }
    __shared__ double sr[4], sf2[4];
    int tid = threadIdx.y * 32 + threadIdx.x;
    int wid = tid >> 6, lane = tid & 63;
    if (lane == 0) { sr[wid] = r2; sf2[wid] = f2; }
    __syncthreads();
    if (tid == 0) {
        long blk = ((long)blockIdx.z * gridDim.y + blockIdx.y) * gridDim.x + blockIdx.x;
        pb[2 * blk]     = sr[0] + sr[1] + sr[2] + sr[3];
        pb[2 * blk + 1] = sf2[0] + sf2[1] + sf2[2] + sf2[3];
    }
}

__global__ void reduce_kernel(const double* __restrict__ pb, long nblk, double* __restrict__ acc)
{
    double r2 = 0.0, f2 = 0.0;
    for (long i = threadIdx.x; i < nblk; i += 256) {
        r2 += pb[2 * i];
        f2 += pb[2 * i + 1];
    }
    for (int off = 32; off > 0; off >>= 1) {
        r2 += __shfl_down(r2, off, 64);
        f2 += __shfl_down(f2, off, 64);
    }
    __shared__ double sr[4], sf2[4];
    int wid = threadIdx.x >> 6, lane = threadIdx.x & 63;
    if (lane == 0) { sr[wid] = r2; sf2[wid] = f2; }
    __syncthreads();
    if (threadIdx.x == 0) {
        acc[0] += sr[0] + sr[1] + sr[2] + sr[3];
        acc[1] += sf2[0] + sf2[1] + sf2[2] + sf2[3];
    }
}

__global__ void finalize_kernel(const double* __restrict__ acc, float* __restrict__ out)
{
    out[0] = (float)sqrt(acc[0] / acc[1]);
}

// ---------------- tiled transpose: out[c][r] = in[r][c] ----------------
__global__ void transpose_kernel(const float* __restrict__ in, float* __restrict__ out,
                                 int R, int C, int ldin, int ldout, long isb, long osb)
{
    __shared__ float t[32][33];
    int z = blockIdx.z;
    in += (long)z * isb; out += (long)z * osb;
    int c0 = blockIdx.x * 32, r0 = blockIdx.y * 32;
    for (int i = threadIdx.y; i < 32; i += 8) {
        int r = r0 + i, c = c0 + threadIdx.x;
        t[i][threadIdx.x] = (r < R && c < C) ? in[(long)r * ldin + c] : 0.f;
    }
    __syncthreads();
    for (int i = threadIdx.y; i < 32; i += 8) {
        int c = c0 + i, r = r0 + threadIdx.x;
        if (c < C && r < R) out[(long)c * ldout + r] = t[threadIdx.x][i];
    }
}

// ---------------- complex 3x3 conv, LDS halo tile ----------------
template<int CIN, int COUT, int INK, int OUTK>
__global__ __launch_bounds__(256, 4) void cconv3(
    const float* __restrict__ in, const float* __restrict__ in2,
    const void* __restrict__ w_r, const void* __restrict__ w_i,
    float* __restrict__ out, float* __restrict__ out2,
    const void* __restrict__ th_r, const void* __restrict__ th_i,
    long in_bs, long out_bs, int tmode, int b0, const int* __restrict__ dmode)
{
    int mode = dmode[0];
    int bz = blockIdx.z;
    int b  = b0 + bz;
    __shared__ float swr[COUT][CIN][9], swi[COUT][CIN][9];
    __shared__ float2 tile[6][66];
    int tid = threadIdx.y * 64 + threadIdx.x;
    if (tid < COUT * CIN * 9) {
        int o = tid / (CIN * 9), rem = tid % (CIN * 9), i = rem / 9, t = rem % 9;
        int dy = t / 3, dx = t % 3;
        float r, im;
        if (!tmode) {
            long idx = (((long)b * COUT + o) * CIN + i) * 9 + t;
            r = ldin(w_r, idx, mode); im = ldin(w_i, idx, mode);
        } else {
            long idx = (((long)b * CIN + i) * COUT + o) * 9 + dx * 3 + dy;
            r = ldin(w_r, idx, mode); im = -ldin(w_i, idx, mode);
        }
        swr[o][i][t] = r; swi[o][i][t] = im;
    }
    int x0 = blockIdx.x * 64, y0 = blockIdx.y * 4;
    int x = x0 + threadIdx.x, y = y0 + threadIdx.y;
    float accr[COUT] = {}, acci[COUT] = {};
    #pragma unroll 1
    for (int i = 0; i < CIN; ++i) {
        __syncthreads();
        const float* pr = in + (long)bz * in_bs + (INK == 1 ? (long)i * 2 * HW2 : (long)i * HW2);
        const float* pi = (INK == 2) ? (in2 + (long)bz * in_bs + (long)i * HW2) : nullptr;
        for (int idx = tid; idx < 66 * 6; idx += 256) {
            int ly = idx / 66, lx = idx % 66;
            int gy = y0 - 1 + ly, gx = x0 - 1 + lx;
            float2 v; v.x = 0.f; v.y = 0.f;
            if (gy >= 0 && gy < HW && gx >= 0 && gx < HW) {
                long gi = (long)gy * HW + gx;
                if (INK == 0) v.x = pr[gi];
                else if (INK == 1) v = ((const float2*)pr)[gi];
                else { v.x = pr[gi]; v.y = pi[gi]; }
            }
            tile[ly][lx] = v;
        }
        __syncthreads();
        #pragma unroll
        for (int dy = 0; dy < 3; ++dy) {
            #pragma unroll
            for (int dx = 0; dx < 3; ++dx) {
                float2 v = tile[threadIdx.y + dy][threadIdx.x + dx];
                int t = dy * 3 + dx;
                #pragma unroll
                for (int o = 0; o < COUT; ++o) {
                    float wr = swr[o][i][t], wi = swi[o][i][t];
                    accr[o] += v.x * wr;
                    acci[o] += v.x * wi;
                    if (INK != 0) { accr[o] -= v.y * wi; acci[o] += v.y * wr; }
                }
            }
        }
    }
    if (x >= HW || y >= HW) return;
    #pragma unroll
    for (int o = 0; o < COUT; ++o) {
        float ar = accr[o], ai = acci[o];
        if (th_r) {
            float tr = ldin(th_r, (long)b * HW2 + (long)y * HW + x, mode);
            float ti = ldin(th_i, (long)b * HW2 + (long)y * HW + x, mode);
            float nr = ar * tr - ai * ti, ni = ar * ti + ai * tr;
            ar = nr; ai = ni;
        }
        if (OUTK == 0) {
            float2 v; v.x = ar; v.y = ai;
            ((float2*)(out + (long)bz * out_bs + (long)o * 2 * HW2))[(long)y * HW + x] = v;
        } else {
            long oo = (long)bz * out_bs + (long)o * HW2 + (long)y * HW + x;
            out[oo]  = ar;
            out2[oo] = ai;
        }
    }
}

// ---------------- MFMA GEMM, fp32 via bf16 split-3; B ALWAYS stored N x K ----------------
// LDS row stride 40 shorts (80 B = 20 banks): fragment b128 reads <=2-way aliased (free).
#define GM 64
#define GN 64
#define GK 32
#define LK 40
__global__ __launch_bounds__(256) void gemm_mfma(
    const float* __restrict__ A, const float* __restrict__ B, float* __restrict__ C,
    int M, int N, int K, int lda, int ldb, int ldc,
    long asb, long bsb, long csb, float alpha, int beta)
{
    int z = blockIdx.z;
    A += (long)z * asb; B += (long)z * bsb; C += (long)z * csb;
    __shared__ short Ah[GM * LK], Al[GM * LK], Bh[GN * LK], Bl[GN * LK];
    int tid = threadIdx.x;
    int wave = tid >> 6, lane = tid & 63;
    int wm = (wave & 1) * 32, wn = (wave >> 1) * 32;
    int lr = lane & 15, lq = lane >> 4;
    int m0 = blockIdx.y * GM, n0 = blockIdx.x * GN;
    int row = tid >> 2, kk = (tid & 3) * 8;
    float4v acc[2][2] = {};

    for (int k0 = 0; k0 < K; k0 += GK) {
        {   // A tile: row m, 8 consecutive k -> one b128 write per array
            int gm = m0 + row;
            const float* ap = A + (long)gm * lda + k0 + kk;
            short8 h8, l8;
            #pragma unroll
            for (int j = 0; j < 8; ++j) {
                int gk = k0 + kk + j;
                float v = (gm < M && gk < K) ? ap[j] : 0.f;
                short h = f2bf(v);
                h8[j] = h; l8[j] = f2bf(v - bfs2f(h));
            }
            *(short8*)&Ah[row * LK + kk] = h8;
            *(short8*)&Al[row * LK + kk] = l8;
        }
        {   // B tile (stored N x K): row n, 8 consecutive k
            int gn = n0 + row;
            const float* bp = B + (long)gn * ldb + k0 + kk;
            short8 h8, l8;
            #pragma unroll
            for (int j = 0; j < 8; ++j) {
                int gk = k0 + kk + j;
                float v = (gn < N && gk < K) ? bp[j] : 0.f;
                short h = f2bf(v);
                h8[j] = h; l8[j] = f2bf(v - bfs2f(h));
            }
            *(short8*)&Bh[row * LK + kk] = h8;
            *(short8*)&Bl[row * LK + kk] = l8;
        }
        __syncthreads();
        short8 ah[2], al[2], bh[2], bl[2];
        #pragma unroll
        for (int mt = 0; mt < 2; ++mt) {
            int mloc = wm + mt * 16 + lr;
            ah[mt] = *(const short8*)&Ah[mloc * LK + lq * 8];
            al[mt] = *(const short8*)&Al[mloc * LK + lq * 8];
        }
        #pragma unroll
        for (int nt = 0; nt < 2; ++nt) {
            int nloc = wn + nt * 16 + lr;
            bh[nt] = *(const short8*)&Bh[nloc * LK + lq * 8];
            bl[nt] = *(const short8*)&Bl[nloc * LK + lq * 8];
        }
        #pragma unroll
        for (int mt = 0; mt < 2; ++mt)
            #pragma unroll
            for (int nt = 0; nt < 2; ++nt) {
                acc[mt][nt] = __builtin_amdgcn_mfma_f32_16x16x32_bf16(ah[mt], bh[nt], acc[mt][nt], 0, 0, 0);
                acc[mt][nt] = __builtin_amdgcn_mfma_f32_16x16x32_bf16(ah[mt], bl[nt], acc[mt][nt], 0, 0, 0);
                acc[mt][nt] = __builtin_amdgcn_mfma_f32_16x16x32_bf16(al[mt], bh[nt], acc[mt][nt], 0, 0, 0);
            }
        __syncthreads();
    }
    #pragma unroll
    for (int mt = 0; mt < 2; ++mt)
        #pragma unroll
        for (int nt = 0; nt < 2; ++nt)
            #pragma unroll
            for (int r = 0; r < 4; ++r) {
                int gm = m0 + wm + mt * 16 + lq * 4 + r;
                int gn = n0 + wn + nt * 16 + lr;
                if (gm < M && gn < N) {
                    float v = alpha * acc[mt][nt][r];
                    if (beta) v += C[(long)gm * ldc + gn];
                    C[(long)gm * ldc + gn] = v;
                }
            }
}

extern "C" void kernel_launch(void* const* d_in, const int* in_sizes, int n_in,
                              void* d_out, int out_size, void* d_ws, size_t ws_size,
                              hipStream_t stream)
{
    const void* f    = d_in[0];
    const void* coef = d_in[1];
    const void* W1r[2] = {d_in[2],  d_in[8]};
    const void* W1i[2] = {d_in[3],  d_in[9]};
    const void* W2r[2] = {d_in[4],  d_in[10]};
    const void* W2i[2] = {d_in[5],  d_in[11]};
    const void* W3r[2] = {d_in[6],  d_in[12]};
    const void* W3i[2] = {d_in[7],  d_in[13]};
    const void* THr[2] = {d_in[14], d_in[16]};
    const void* THi[2] = {d_in[15], d_in[17]};

    sentinel_kernel<<<1, 64, 0, stream>>>((float*)d_out);

    // ---- exact ws accounting; pick largest chunk cb in {8,4,2,1} that fits ----
    const size_t PERSIST = 128 + 32768 + 260672 + 521280 + 521280;
    const size_t PERB    = 2 * 262144 + 4 * 260160 + 260672 + 521280
                         + 261184 + 2 * 522304 + 2 * 2089152;
    size_t ws_floats = ws_size / sizeof(float);
    int cb = 8;
    while (cb > 1 && PERSIST + (size_t)cb * PERB > ws_floats) cb >>= 1;

    float* ws = (float*)d_ws;
    size_t off = 0;
    auto alloc = [&](size_t n) { size_t o = off; off += (n + 63) & ~(size_t)63; return ws + o; };
    double* acc  = (double*)alloc(64);
    int*   dmode = (int*)alloc(64);
    double* pb   = (double*)alloc(32768);
    float* Sf   = alloc(511L * 510);
    float* CS   = alloc(510L * 1022);
    float* CS2  = alloc(510L * 1022);
    float* xcur = alloc((size_t)cb * NN2);
    float* xnxt = alloc((size_t)cb * NN2);
    float* r1   = alloc((size_t)cb * MM2);
    float* r1T  = alloc((size_t)cb * MM2);
    float* F1c  = alloc((size_t)cb * MM2);
    float* F2c  = alloc((size_t)cb * MM2);
    float* T1   = alloc((size_t)cb * 511 * 510);
    float* XY   = alloc((size_t)cb * 510 * 1022);
    float* G    = alloc((size_t)cb * HW2);
    float* outRI  = alloc((size_t)cb * 2 * HW2);
    float* outRIT = alloc((size_t)cb * 511 * 1022);   // [R col | I col] rows, ld=1022
    float* bufA = alloc((size_t)cb * 8 * HW2);
    float* bufB = alloc((size_t)cb * 8 * HW2);

    detect_kernel<<<1, 256, 0, stream>>>(f, dmode);
    zerod_kernel<<<1, 64, 0, stream>>>(acc);
    basis_kernel<<<dim3((510 * 1022 + 255) / 256), 256, 0, stream>>>(Sf, CS, CS2);

    dim3 blk(32, 8);
    dim3 gridc(16, 64, cb);
    dim3 cblk(64, 4);
    dim3 cgrid(8, 128, cb);
    dim3 tblk(32, 8);

    auto gemm = [&](const float* A, const float* B, float* C, int M, int N, int K,
                    int lda, int ldb, int ldc, long asb, long bsb, long csb,
                    float alpha, int beta) {
        dim3 g((N + GN - 1) / GN, (M + GM - 1) / GM, cb);
        gemm_mfma<<<g, 256, 0, stream>>>(A, B, C, M, N, K, lda, ldb, ldc, asb, bsb, csb, alpha, beta);
    };

    const float cfwd = -4.0f / 1044484.0f;  // -4/1022^2

    for (int b0 = 0; b0 < 8; b0 += cb) {
        // x1 = w*f, then 9 more Richardson iterations (10 total)
        initx_kernel<<<gridc, blk, 0, stream>>>(xcur, f, b0, dmode);
        float* cur = xcur; float* nxt = xnxt;
        for (int it = 0; it < 9; ++it) {
            rich_kernel<<<gridc, blk, 0, stream>>>(cur, nxt, f, coef, b0, dmode);
            float* t = cur; cur = nxt; nxt = t;
        }
        resid_kernel<<<gridc, blk, 0, stream>>>(cur, f, coef, r1, b0, dmode);
        transpose_kernel<<<dim3(16, 16, cb), tblk, 0, stream>>>(r1, r1T, MM, MM, MM, MM, MM2, MM2);

        // forward sine transform: G = cfwd * Sf * r1 * Sf^T   (all GEMMs bT)
        gemm(Sf, r1T, T1, 511, 510, 510, 510, 510, 510, 0, MM2, 511L * 510, 1.f, 0);
        gemm(T1, Sf, G, 511, 511, 510, 510, 510, 511, 511L * 510, 0, HW2, cfwd, 0);

        for (int t = 0; t < 2; ++t) {
            // forward chain: G(real) -> bufA(int) -> bufB(int) -> outRI(planar,*theta)
            cconv3<1, 4, 0, 0><<<cgrid, cblk, 0, stream>>>(
                G, nullptr, W1r[t], W1i[t], bufA, nullptr, nullptr, nullptr,
                HW2, 8L * HW2, 0, b0, dmode);
            cconv3<4, 4, 1, 0><<<cgrid, cblk, 0, stream>>>(
                bufA, nullptr, W2r[t], W2i[t], bufB, nullptr, nullptr, nullptr,
                8L * HW2, 8L * HW2, 0, b0, dmode);
            cconv3<4, 1, 1, 1><<<cgrid, cblk, 0, stream>>>(
                bufB, nullptr, W3r[t], W3i[t], outRI, outRI + HW2, THr[t], THi[t],
                8L * HW2, 2L * HW2, 0, b0, dmode);
            // transposed-conj chain
            cconv3<1, 4, 2, 0><<<cgrid, cblk, 0, stream>>>(
                outRI, outRI + HW2, W3r[t], W3i[t], bufA, nullptr, nullptr, nullptr,
                2L * HW2, 8L * HW2, 1, b0, dmode);
            cconv3<4, 4, 1, 0><<<cgrid, cblk, 0, stream>>>(
                bufA, nullptr, W2r[t], W2i[t], bufB, nullptr, nullptr, nullptr,
                8L * HW2, 8L * HW2, 1, b0, dmode);
            cconv3<4, 1, 1, 1><<<cgrid, cblk, 0, stream>>>(
                bufB, nullptr, W1r[t], W1i[t], outRI, outRI + HW2, nullptr, nullptr,
                8L * HW2, 2L * HW2, 1, b0, dmode);

            // outRIT[x][k] = (k<511 ? R[k][x] : I[k-511][x]); rows x, ld 1022
            transpose_kernel<<<dim3(16, 16, cb), tblk, 0, stream>>>(
                outRI, outRIT, HW, HW, HW, 1022, 2L * HW2, 511L * 1022);
            transpose_kernel<<<dim3(16, 16, cb), tblk, 0, stream>>>(
                outRI + HW2, outRIT + 511, HW, HW, HW, 1022, 2L * HW2, 511L * 1022);

            // inverse: X = CS*[R;I], Y = CS2*[R;I] (into XY halves), F = [X|Y]*CS^T
            float* Ft = (t == 0) ? F1c : F2c;
            gemm(CS,  outRIT, XY,       510, 511, 1022, 1022, 1022, 1022, 0, 511L * 1022, 510L * 1022, 1.f, 0);
            gemm(CS2, outRIT, XY + 511, 510, 511, 1022, 1022, 1022, 1022, 0, 511L * 1022, 510L * 1022, 1.f, 0);
            gemm(XY, CS, Ft, 510, 510, 1022, 1022, 1022, 510, 510L * 1022, 0, MM2, 1.f, 0);
        }

        update_kernel<<<gridc, blk, 0, stream>>>(cur, coef, F1c, F2c, b0, dmode);
        norm_kernel<<<gridc, blk, 0, stream>>>(cur, f, coef, pb, b0, dmode);
        reduce_kernel<<<1, 256, 0, stream>>>(pb, (long)1024 * cb, acc);
    }

    finalize_kernel<<<1, 1, 0, stream>>>(acc, (float*)d_out);
}

// Round 11
// 1052.188 us; speedup vs baseline: 8.4979x; 1.3727x over previous
//
#include <hip/hip_runtime.h>
#include <hip/hip_bf16.h>
#include <math.h>

#define HW   511
#define HW2  261121      // 511*511
#define MM   510
#define MM2  260100      // 510*510
#define NN   512
#define NN2  262144      // 512*512
#define PI_D 3.14159265358979323846

typedef __attribute__((ext_vector_type(8))) short short8;
typedef __attribute__((ext_vector_type(4))) float float4v;

__device__ __forceinline__ float bf2f(const __hip_bfloat16 v) { return __bfloat162float(v); }

__device__ __forceinline__ float ldin(const void* p, long i, int mode)
{
    return mode ? ((const float*)p)[i] : bf2f(((const __hip_bfloat16*)p)[i]);
}

__device__ __forceinline__ short f2bf(float v)
{
    unsigned u = __builtin_bit_cast(unsigned, v);
    u += 0x7FFF + ((u >> 16) & 1);
    return (short)(u >> 16);
}
__device__ __forceinline__ float bfs2f(short s)
{
    unsigned u = ((unsigned)(unsigned short)s) << 16;
    return __builtin_bit_cast(float, u);
}

__global__ void detect_kernel(const void* __restrict__ f, int* __restrict__ mode)
{
    __shared__ int cnt;
    if (threadIdx.x == 0) cnt = 0;
    __syncthreads();
    float v = ((const float*)f)[threadIdx.x];
    float a = fabsf(v);
    int sane = (isfinite(v) && a > 1e-6f && a < 100.f) ? 1 : 0;
    atomicAdd(&cnt, sane);
    __syncthreads();
    if (threadIdx.x == 0) mode[0] = (cnt >= 128) ? 1 : 0;
}

__global__ void sentinel_kernel(float* __restrict__ out) { out[0] = 0.25f; }

__global__ void zerod_kernel(double* __restrict__ p)
{
    if (threadIdx.x < 2) p[threadIdx.x] = 0.0;
}

// ---------------- basis matrices, directly as bf16 hi/lo planes ----------------
// Sf plane: 511 rows x 512 (k), Sf[a][m]=sin(pi*(a-255)*(m+1)/511), pad m=510,511 -> 0
// CS plane: 510 rows x 1024: [C | S] cols 0..1021, pad 1022,1023 -> 0
// CS2: [-S | C] likewise.
__global__ void basisHL_kernel(short* __restrict__ SfH, short* __restrict__ SfL,
                               short* __restrict__ CSH, short* __restrict__ CSL,
                               short* __restrict__ CS2H, short* __restrict__ CS2L)
{
    int idx = blockIdx.x * 256 + threadIdx.x;
    if (idx < 511 * 512) {
        int a = idx / 512, m = idx % 512;
        float v = 0.f;
        if (m < 510) v = (float)sin(PI_D * (double)(a - 255) * (double)(m + 1) / 511.0);
        short h = f2bf(v);
        SfH[idx] = h; SfL[idx] = f2bf(v - bfs2f(h));
    }
    if (idx < 510 * 1024) {
        int p = idx / 1024, a = idx % 1024;
        float c = 0.f, c2 = 0.f;
        if (a < 1022) {
            if (a < 511) {
                double ang = PI_D * (double)p * (double)(a - 255) / 511.0;
                c = (float)cos(ang); c2 = (float)(-sin(ang));
            } else {
                double ang = PI_D * (double)p * (double)(a - 511 - 255) / 511.0;
                c = (float)sin(ang); c2 = (float)cos(ang);
            }
        }
        short h = f2bf(c);
        CSH[idx] = h; CSL[idx] = f2bf(c - bfs2f(h));
        h = f2bf(c2);
        CS2H[idx] = h; CS2L[idx] = f2bf(c2 - bfs2f(h));
    }
}

// zero col 1023 of XY planes (never written by the gemms)
__global__ void zerocol_kernel(short* __restrict__ XH, short* __restrict__ XL, long csb)
{
    int z = blockIdx.x;
    int t = threadIdx.x;
    if (t < 510) {
        XH[(long)z * csb + (long)t * 1024 + 1023] = 0;
        XL[(long)z * csb + (long)t * 1024 + 1023] = 0;
    }
}

// ---------------- 5-point stencil A ----------------
__device__ __forceinline__ float computeA(const float* __restrict__ xb,
                                          const void* __restrict__ cb,
                                          int p, int q, int mode)
{
    if (p < 1 || p > 510 || q < 1 || q > 510) return 0.f;
    int i = p - 1, j = q - 1;
    float a   = ldin(cb, (long)i * MM + j, mode);
    float aw  = ldin(cb, (long)i * MM + (j > 0 ? j - 1 : 0), mode);
    float ae  = ldin(cb, (long)i * MM + (j < MM - 1 ? j + 1 : MM - 1), mode);
    float an  = ldin(cb, (long)(i < MM - 1 ? i + 1 : MM - 1) * MM + j, mode);
    float as_ = ldin(cb, (long)(i > 0 ? i - 1 : 0) * MM + j, mode);
    float sw = -2.f * aw  * a / (aw  + a);
    float se = -2.f * ae  * a / (ae  + a);
    float sn = -2.f * an  * a / (an  + a);
    float ss = -2.f * as_ * a / (as_ + a);
    float sc = -(sw + se + sn + ss);
    return ss * xb[(p - 1) * NN + q] + sw * xb[p * NN + q - 1] + sc * xb[p * NN + q]
         + se * xb[p * NN + q + 1] + sn * xb[(p + 1) * NN + q];
}

__global__ void initx_kernel(float* __restrict__ x, const void* __restrict__ f,
                             int b0, const int* __restrict__ dmode)
{
    int mode = dmode[0];
    int q = blockIdx.x * 32 + threadIdx.x;
    int p = blockIdx.y * 8 + threadIdx.y;
    int bz = blockIdx.z;
    int b = b0 + bz;
    if (p >= NN || q >= NN) return;
    const char* fc = (const char*)f + ((long)b * NN2 << (mode + 1));
    x[(long)bz * NN2 + p * NN + q] = 0.078125f * ldin(fc, (long)p * NN + q, mode);
}

__global__ void rich_kernel(const float* __restrict__ xin, float* __restrict__ xout,
                            const void* __restrict__ f, const void* __restrict__ coef,
                            int b0, const int* __restrict__ dmode)
{
    int mode = dmode[0];
    int q = blockIdx.x * 32 + threadIdx.x;
    int p = blockIdx.y * 8 + threadIdx.y;
    int bz = blockIdx.z;
    int b = b0 + bz;
    if (p >= NN || q >= NN) return;
    long xo = (long)bz * NN2;
    const char* cc = (const char*)coef + ((long)b * MM2 << (mode + 1));
    const char* fc = (const char*)f + ((long)b * NN2 << (mode + 1));
    float Ax = computeA(xin + xo, cc, p, q, mode);
    float fv = ldin(fc, (long)p * NN + q, mode);
    xout[xo + p * NN + q] = xin[xo + p * NN + q] + 0.078125f * (fv - Ax);
}

__global__ void resid_kernel(const float* __restrict__ x,
                             const void* __restrict__ f, const void* __restrict__ coef,
                             float* __restrict__ r1, int b0, const int* __restrict__ dmode)
{
    int mode = dmode[0];
    int j = blockIdx.x * 32 + threadIdx.x;
    int i = blockIdx.y * 8 + threadIdx.y;
    int bz = blockIdx.z;
    int b = b0 + bz;
    if (i >= MM || j >= MM) return;
    int p = i + 1, q = j + 1;
    const char* cc = (const char*)coef + ((long)b * MM2 << (mode + 1));
    const char* fc = (const char*)f + ((long)b * NN2 << (mode + 1));
    float Ax = computeA(x + (long)bz * NN2, cc, p, q, mode);
    r1[(long)bz * MM2 + i * MM + j] = ldin(fc, (long)p * NN + q, mode) - Ax;
}

__global__ void update_kernel(float* __restrict__ x,
                              const void* __restrict__ coef,
                              const float* __restrict__ F1, const float* __restrict__ F2,
                              int b0, const int* __restrict__ dmode)
{
    int mode = dmode[0];
    int j = blockIdx.x * 32 + threadIdx.x;
    int i = blockIdx.y * 8 + threadIdx.y;
    int bz = blockIdx.z;
    int b = b0 + bz;
    if (i >= MM || j >= MM) return;
    float cf = ldin(coef, (long)b * MM2 + i * MM + j, mode);
    long o = (long)bz * MM2 + i * MM + j;
    float e = (cf < 1.0f) ? (F1[o] / cf) : (F2[o] * cf);
    x[(long)bz * NN2 + (i + 1) * NN + (j + 1)] += e;
}

__global__ void norm_kernel(const float* __restrict__ x,
                            const void* __restrict__ f, const void* __restrict__ coef,
                            double* __restrict__ pb, int b0, const int* __restrict__ dmode)
{
    int mode = dmode[0];
    int q = blockIdx.x * 32 + threadIdx.x;
    int p = blockIdx.y * 8 + threadIdx.y;
    int bz = blockIdx.z;
    int b = b0 + bz;
    double r2 = 0.0, f2 = 0.0;
    if (p < NN && q < NN) {
        const char* cc = (const char*)coef + ((long)b * MM2 << (mode + 1));
        const char* fc = (const char*)f + ((long)b * NN2 << (mode + 1));
        float Ax = computeA(x + (long)bz * NN2, cc, p, q, mode);
        float fv = ldin(fc, (long)p * NN + q, mode);
        float rv = fv - Ax;
        r2 = (double)rv * (double)rv;
        f2 = (double)fv * (double)fv;
    }
    for (int off = 32; off > 0; off >>= 1) {
        r2 += __shfl_down(r2, off, 64);
        f2 += __shfl_down(f2, off, 64);
    }
    __shared__ double sr[4], sf2[4];
    int tid = threadIdx.y * 32 + threadIdx.x;
    int wid = tid >> 6, lane = tid & 63;
    if (lane == 0) { sr[wid] = r2; sf2[wid] = f2; }
    __syncthreads();
    if (tid == 0) {
        long blk = ((long)blockIdx.z * gridDim.y + blockIdx.y) * gridDim.x + blockIdx.x;
        pb[2 * blk]     = sr[0] + sr[1] + sr[2] + sr[3];
        pb[2 * blk + 1] = sf2[0] + sf2[1] + sf2[2] + sf2[3];
    }
}

__global__ void reduce_kernel(const double* __restrict__ pb, long nblk, double* __restrict__ acc)
{
    double r2 = 0.0, f2 = 0.0;
    for (long i = threadIdx.x; i < nblk; i += 256) {
        r2 += pb[2 * i];
        f2 += pb[2 * i + 1];
    }
    for (int off = 32; off > 0; off >>= 1) {
        r2 += __shfl_down(r2, off, 64);
        f2 += __shfl_down(f2, off, 64);
    }
    __shared__ double sr[4], sf2[4];
    int wid = threadIdx.x >> 6, lane = threadIdx.x & 63;
    if (lane == 0) { sr[wid] = r2; sf2[wid] = f2; }
    __syncthreads();
    if (threadIdx.x == 0) {
        acc[0] += sr[0] + sr[1] + sr[2] + sr[3];
        acc[1] += sf2[0] + sf2[1] + sf2[2] + sf2[3];
    }
}

__global__ void finalize_kernel(const double* __restrict__ acc, float* __restrict__ out)
{
    out[0] = (float)sqrt(acc[0] / acc[1]);
}

// ---------------- fused transpose + hi/lo split ----------------
// outH/L[c*ldk + kofs + r] = split(in[r*ldin + c]) for r<R (0 for R<=r<Rpad), c<C
__global__ void transposeHL_kernel(const float* __restrict__ in,
                                   short* __restrict__ H, short* __restrict__ L,
                                   int R, int C, int ldin, int ldk, int kofs, int Rpad,
                                   long isb, long osb)
{
    __shared__ float t[32][33];
    int z = blockIdx.z;
    in += (long)z * isb;
    H += (long)z * osb + kofs;
    L += (long)z * osb + kofs;
    int c0 = blockIdx.x * 32, r0 = blockIdx.y * 32;
    for (int i = threadIdx.y; i < 32; i += 8) {
        int r = r0 + i, c = c0 + threadIdx.x;
        t[i][threadIdx.x] = (r < R && c < C) ? in[(long)r * ldin + c] : 0.f;
    }
    __syncthreads();
    for (int i = threadIdx.y; i < 32; i += 8) {
        int c = c0 + i, r = r0 + threadIdx.x;
        if (c < C && r < Rpad) {
            float v = t[threadIdx.x][i];
            short h = f2bf(v);
            H[(long)c * ldk + r] = h;
            L[(long)c * ldk + r] = f2bf(v - bfs2f(h));
        }
    }
}

// ---------------- MFMA GEMM on precomputed hi/lo planes ----------------
// C = alpha * A * B^T, A: M x Kpad plane (hi/lo), B: N x Kpad plane.
// outHL=0: float C (ldc); outHL=1: write hi/lo planes CH/CL (ldcS), zeros for gn in [N,Npad).
#define GM 64
#define GN 64
#define GK2 64
#define LK2 72
__global__ __launch_bounds__(256) void gemm_hl(
    const short* __restrict__ AH, const short* __restrict__ AL, int ldaS,
    const short* __restrict__ BH, const short* __restrict__ BL, int ldbS,
    float* __restrict__ C, int ldc,
    short* __restrict__ CH, short* __restrict__ CL, int ldcS, int Npad,
    int M, int N, int Kpad,
    long asb, long bsb, long csb, float alpha, int outHL)
{
    int z = blockIdx.z;
    AH += (long)z * asb; AL += (long)z * asb;
    BH += (long)z * bsb; BL += (long)z * bsb;
    if (outHL) { CH += (long)z * csb; CL += (long)z * csb; }
    else       { C  += (long)z * csb; }
    __shared__ short Ah[GM * LK2], Al[GM * LK2], Bh[GN * LK2], Bl[GN * LK2];
    int tid = threadIdx.x;
    int wave = tid >> 6, lane = tid & 63;
    int wm = (wave & 1) * 32, wn = (wave >> 1) * 32;
    int lr = lane & 15, lq = lane >> 4;
    int m0 = blockIdx.y * GM, n0 = blockIdx.x * GN;
    int row = tid >> 2, kk = (tid & 3) * 16;
    float4v acc[2][2] = {};
    short8 z8 = {};

    for (int k0 = 0; k0 < Kpad; k0 += GK2) {
        {   // A rows
            short8 h0 = z8, h1 = z8, l0 = z8, l1 = z8;
            if (m0 + row < M) {
                long o = (long)(m0 + row) * ldaS + k0 + kk;
                h0 = *(const short8*)&AH[o]; h1 = *(const short8*)&AH[o + 8];
                l0 = *(const short8*)&AL[o]; l1 = *(const short8*)&AL[o + 8];
            }
            *(short8*)&Ah[row * LK2 + kk]     = h0;
            *(short8*)&Ah[row * LK2 + kk + 8] = h1;
            *(short8*)&Al[row * LK2 + kk]     = l0;
            *(short8*)&Al[row * LK2 + kk + 8] = l1;
        }
        {   // B rows
            short8 h0 = z8, h1 = z8, l0 = z8, l1 = z8;
            if (n0 + row < N) {
                long o = (long)(n0 + row) * ldbS + k0 + kk;
                h0 = *(const short8*)&BH[o]; h1 = *(const short8*)&BH[o + 8];
                l0 = *(const short8*)&BL[o]; l1 = *(const short8*)&BL[o + 8];
            }
            *(short8*)&Bh[row * LK2 + kk]     = h0;
            *(short8*)&Bh[row * LK2 + kk + 8] = h1;
            *(short8*)&Bl[row * LK2 + kk]     = l0;
            *(short8*)&Bl[row * LK2 + kk + 8] = l1;
        }
        __syncthreads();
        #pragma unroll
        for (int ks = 0; ks < GK2; ks += 32) {
            short8 ah[2], al[2], bh[2], bl[2];
            #pragma unroll
            for (int mt = 0; mt < 2; ++mt) {
                int mloc = wm + mt * 16 + lr;
                ah[mt] = *(const short8*)&Ah[mloc * LK2 + ks + lq * 8];
                al[mt] = *(const short8*)&Al[mloc * LK2 + ks + lq * 8];
            }
            #pragma unroll
            for (int nt = 0; nt < 2; ++nt) {
                int nloc = wn + nt * 16 + lr;
                bh[nt] = *(const short8*)&Bh[nloc * LK2 + ks + lq * 8];
                bl[nt] = *(const short8*)&Bl[nloc * LK2 + ks + lq * 8];
            }
            #pragma unroll
            for (int mt = 0; mt < 2; ++mt)
                #pragma unroll
                for (int nt = 0; nt < 2; ++nt) {
                    acc[mt][nt] = __builtin_amdgcn_mfma_f32_16x16x32_bf16(ah[mt], bh[nt], acc[mt][nt], 0, 0, 0);
                    acc[mt][nt] = __builtin_amdgcn_mfma_f32_16x16x32_bf16(ah[mt], bl[nt], acc[mt][nt], 0, 0, 0);
                    acc[mt][nt] = __builtin_amdgcn_mfma_f32_16x16x32_bf16(al[mt], bh[nt], acc[mt][nt], 0, 0, 0);
                }
        }
        __syncthreads();
    }
    #pragma unroll
    for (int mt = 0; mt < 2; ++mt)
        #pragma unroll
        for (int nt = 0; nt < 2; ++nt)
            #pragma unroll
            for (int r = 0; r < 4; ++r) {
                int gm = m0 + wm + mt * 16 + lq * 4 + r;
                int gn = n0 + wn + nt * 16 + lr;
                if (gm >= M) continue;
                if (!outHL) {
                    if (gn < N) C[(long)gm * ldc + gn] = alpha * acc[mt][nt][r];
                } else {
                    if (gn < Npad) {
                        float v = (gn < N) ? alpha * acc[mt][nt][r] : 0.f;
                        short h = f2bf(v);
                        CH[(long)gm * ldcS + gn] = h;
                        CL[(long)gm * ldcS + gn] = f2bf(v - bfs2f(h));
                    }
                }
            }
}

// ---------------- complex 3x3 conv, LDS halo tile ----------------
template<int CIN, int COUT, int INK, int OUTK>
__global__ __launch_bounds__(256, 4) void cconv3(
    const float* __restrict__ in, const float* __restrict__ in2,
    const void* __restrict__ w_r, const void* __restrict__ w_i,
    float* __restrict__ out, float* __restrict__ out2,
    const void* __restrict__ th_r, const void* __restrict__ th_i,
    long in_bs, long out_bs, int tmode, int b0, const int* __restrict__ dmode)
{
    int mode = dmode[0];
    int bz = blockIdx.z;
    int b  = b0 + bz;
    __shared__ float swr[COUT][CIN][9], swi[COUT][CIN][9];
    __shared__ float2 tile[6][66];
    int tid = threadIdx.y * 64 + threadIdx.x;
    if (tid < COUT * CIN * 9) {
        int o = tid / (CIN * 9), rem = tid % (CIN * 9), i = rem / 9, t = rem % 9;
        int dy = t / 3, dx = t % 3;
        float r, im;
        if (!tmode) {
            long idx = (((long)b * COUT + o) * CIN + i) * 9 + t;
            r = ldin(w_r, idx, mode); im = ldin(w_i, idx, mode);
        } else {
            long idx = (((long)b * CIN + i) * COUT + o) * 9 + dx * 3 + dy;
            r = ldin(w_r, idx, mode); im = -ldin(w_i, idx, mode);
        }
        swr[o][i][t] = r; swi[o][i][t] = im;
    }
    int x0 = blockIdx.x * 64, y0 = blockIdx.y * 4;
    int x = x0 + threadIdx.x, y = y0 + threadIdx.y;
    float accr[COUT] = {}, acci[COUT] = {};
    #pragma unroll 1
    for (int i = 0; i < CIN; ++i) {
        __syncthreads();
        const float* pr = in + (long)bz * in_bs + (INK == 1 ? (long)i * 2 * HW2 : (long)i * HW2);
        const float* pi = (INK == 2) ? (in2 + (long)bz * in_bs + (long)i * HW2) : nullptr;
        for (int idx = tid; idx < 66 * 6; idx += 256) {
            int ly = idx / 66, lx = idx % 66;
            int gy = y0 - 1 + ly, gx = x0 - 1 + lx;
            float2 v; v.x = 0.f; v.y = 0.f;
            if (gy >= 0 && gy < HW && gx >= 0 && gx < HW) {
                long gi = (long)gy * HW + gx;
                if (INK == 0) v.x = pr[gi];
                else if (INK == 1) v = ((const float2*)pr)[gi];
                else { v.x = pr[gi]; v.y = pi[gi]; }
            }
            tile[ly][lx] = v;
        }
        __syncthreads();
        #pragma unroll
        for (int dy = 0; dy < 3; ++dy) {
            #pragma unroll
            for (int dx = 0; dx < 3; ++dx) {
                float2 v = tile[threadIdx.y + dy][threadIdx.x + dx];
                int t = dy * 3 + dx;
                #pragma unroll
                for (int o = 0; o < COUT; ++o) {
                    float wr = swr[o][i][t], wi = swi[o][i][t];
                    accr[o] += v.x * wr;
                    acci[o] += v.x * wi;
                    if (INK != 0) { accr[o] -= v.y * wi; acci[o] += v.y * wr; }
                }
            }
        }
    }
    if (x >= HW || y >= HW) return;
    #pragma unroll
    for (int o = 0; o < COUT; ++o) {
        float ar = accr[o], ai = acci[o];
        if (th_r) {
            float tr = ldin(th_r, (long)b * HW2 + (long)y * HW + x, mode);
            float ti = ldin(th_i, (long)b * HW2 + (long)y * HW + x, mode);
            float nr = ar * tr - ai * ti, ni = ar * ti + ai * tr;
            ar = nr; ai = ni;
        }
        if (OUTK == 0) {
            float2 v; v.x = ar; v.y = ai;
            ((float2*)(out + (long)bz * out_bs + (long)o * 2 * HW2))[(long)y * HW + x] = v;
        } else {
            long oo = (long)bz * out_bs + (long)o * HW2 + (long)y * HW + x;
            out[oo]  = ar;
            out2[oo] = ai;
        }
    }
}

extern "C" void kernel_launch(void* const* d_in, const int* in_sizes, int n_in,
                              void* d_out, int out_size, void* d_ws, size_t ws_size,
                              hipStream_t stream)
{
    const void* f    = d_in[0];
    const void* coef = d_in[1];
    const void* W1r[2] = {d_in[2],  d_in[8]};
    const void* W1i[2] = {d_in[3],  d_in[9]};
    const void* W2r[2] = {d_in[4],  d_in[10]};
    const void* W2i[2] = {d_in[5],  d_in[11]};
    const void* W3r[2] = {d_in[6],  d_in[12]};
    const void* W3i[2] = {d_in[7],  d_in[13]};
    const void* THr[2] = {d_in[14], d_in[16]};
    const void* THi[2] = {d_in[15], d_in[17]};

    sentinel_kernel<<<1, 64, 0, stream>>>((float*)d_out);

    // ---- ws accounting ----
    const size_t PERSIST = 1330000;   // acc/dmode/pb + SfHL + CSHL + CS2HL
    const size_t PERB    = 7900000;   // see layout below
    size_t ws_floats = ws_size / sizeof(float);
    int cb = 8;
    while (cb > 1 && PERSIST + (size_t)cb * PERB > ws_floats) cb >>= 1;

    float* ws = (float*)d_ws;
    size_t off = 0;
    auto alloc = [&](size_t n) { size_t o = off; off += (n + 63) & ~(size_t)63; return ws + o; };
    auto salloc = [&](size_t nshorts) { return (short*)alloc((nshorts + 1) / 2); };
    double* acc  = (double*)alloc(64);
    int*   dmode = (int*)alloc(64);
    double* pb   = (double*)alloc(32768);
    short* SfH  = salloc(511L * 512); short* SfL  = salloc(511L * 512);
    short* CSH  = salloc(510L * 1024); short* CSL  = salloc(510L * 1024);
    short* CS2H = salloc(510L * 1024); short* CS2L = salloc(510L * 1024);
    float* xcur = alloc((size_t)cb * NN2);
    float* xnxt = alloc((size_t)cb * NN2);
    float* r1   = alloc((size_t)cb * MM2);
    float* F1c  = alloc((size_t)cb * MM2);
    float* F2c  = alloc((size_t)cb * MM2);
    float* G    = alloc((size_t)cb * HW2);
    float* outRI  = alloc((size_t)cb * 2 * HW2);
    float* bufA = alloc((size_t)cb * 8 * HW2);
    float* bufB = alloc((size_t)cb * 8 * HW2);
    short* r1TH = salloc((size_t)cb * 510 * 512); short* r1TL = salloc((size_t)cb * 510 * 512);
    short* T1H  = salloc((size_t)cb * 511 * 512); short* T1L  = salloc((size_t)cb * 511 * 512);
    short* oRTH = salloc((size_t)cb * 511 * 1024); short* oRTL = salloc((size_t)cb * 511 * 1024);
    short* XYH  = salloc((size_t)cb * 510 * 1024); short* XYL  = salloc((size_t)cb * 510 * 1024);

    detect_kernel<<<1, 256, 0, stream>>>(f, dmode);
    zerod_kernel<<<1, 64, 0, stream>>>(acc);
    basisHL_kernel<<<dim3((510 * 1024 + 255) / 256), 256, 0, stream>>>(SfH, SfL, CSH, CSL, CS2H, CS2L);

    dim3 blk(32, 8);
    dim3 gridc(16, 64, cb);
    dim3 cblk(64, 4);
    dim3 cgrid(8, 128, cb);
    dim3 tblk(32, 8);

    // strides (shorts / floats)
    const long sb_r1T = 510L * 512, sb_T1 = 511L * 512, sb_oRT = 511L * 1024, sb_XY = 510L * 1024;
    const float cfwd = -4.0f / 1044484.0f;  // -4/1022^2

    auto gemmF = [&](const short* AH_, const short* AL_, int ldaS, long asb,
                     const short* BH_, const short* BL_, int ldbS, long bsb,
                     float* C_, int ldc, long csb,
                     int M, int N, int Kpad, float alpha) {
        dim3 g((N + GN - 1) / GN, (M + GM - 1) / GM, cb);
        gemm_hl<<<g, 256, 0, stream>>>(AH_, AL_, ldaS, BH_, BL_, ldbS,
                                       C_, ldc, nullptr, nullptr, 0, 0,
                                       M, N, Kpad, asb, bsb, csb, alpha, 0);
    };
    auto gemmHL = [&](const short* AH_, const short* AL_, int ldaS, long asb,
                      const short* BH_, const short* BL_, int ldbS, long bsb,
                      short* CH_, short* CL_, int ldcS, long csb,
                      int M, int N, int Npad, int Kpad, float alpha) {
        dim3 g((Npad + GN - 1) / GN, (M + GM - 1) / GM, cb);
        gemm_hl<<<g, 256, 0, stream>>>(AH_, AL_, ldaS, BH_, BL_, ldbS,
                                       nullptr, 0, CH_, CL_, ldcS, Npad,
                                       M, N, Kpad, asb, bsb, csb, alpha, 1);
    };

    for (int b0 = 0; b0 < 8; b0 += cb) {
        initx_kernel<<<gridc, blk, 0, stream>>>(xcur, f, b0, dmode);
        float* cur = xcur; float* nxt = xnxt;
        for (int it = 0; it < 9; ++it) {
            rich_kernel<<<gridc, blk, 0, stream>>>(cur, nxt, f, coef, b0, dmode);
            float* t = cur; cur = nxt; nxt = t;
        }
        resid_kernel<<<gridc, blk, 0, stream>>>(cur, f, coef, r1, b0, dmode);

        // r1T hi/lo planes (510 rows x 512k, pad 2)
        transposeHL_kernel<<<dim3(16, 16, cb), tblk, 0, stream>>>(
            r1, r1TH, r1TL, MM, MM, MM, 512, 0, 512, MM2, sb_r1T);

        // T1 = Sf * r1^T  -> HL planes (511 x 510, pad to 512)
        gemmHL(SfH, SfL, 512, 0, r1TH, r1TL, 512, sb_r1T,
               T1H, T1L, 512, sb_T1, 511, 510, 512, 512, 1.f);
        // G = cfwd * T1 * Sf^T  (float)
        gemmF(T1H, T1L, 512, sb_T1, SfH, SfL, 512, 0,
              G, HW, HW2, 511, 511, 512, cfwd);

        zerocol_kernel<<<cb, 512, 0, stream>>>(XYH, XYL, sb_XY);

        for (int t = 0; t < 2; ++t) {
            cconv3<1, 4, 0, 0><<<cgrid, cblk, 0, stream>>>(
                G, nullptr, W1r[t], W1i[t], bufA, nullptr, nullptr, nullptr,
                HW2, 8L * HW2, 0, b0, dmode);
            cconv3<4, 4, 1, 0><<<cgrid, cblk, 0, stream>>>(
                bufA, nullptr, W2r[t], W2i[t], bufB, nullptr, nullptr, nullptr,
                8L * HW2, 8L * HW2, 0, b0, dmode);
            cconv3<4, 1, 1, 1><<<cgrid, cblk, 0, stream>>>(
                bufB, nullptr, W3r[t], W3i[t], outRI, outRI + HW2, THr[t], THi[t],
                8L * HW2, 2L * HW2, 0, b0, dmode);
            cconv3<1, 4, 2, 0><<<cgrid, cblk, 0, stream>>>(
                outRI, outRI + HW2, W3r[t], W3i[t], bufA, nullptr, nullptr, nullptr,
                2L * HW2, 8L * HW2, 1, b0, dmode);
            cconv3<4, 4, 1, 0><<<cgrid, cblk, 0, stream>>>(
                bufA, nullptr, W2r[t], W2i[t], bufB, nullptr, nullptr, nullptr,
                8L * HW2, 8L * HW2, 1, b0, dmode);
            cconv3<4, 1, 1, 1><<<cgrid, cblk, 0, stream>>>(
                bufB, nullptr, W1r[t], W1i[t], outRI, outRI + HW2, nullptr, nullptr,
                8L * HW2, 2L * HW2, 1, b0, dmode);

            // outRI^T hi/lo planes: rows x (511) x 1024k; R cols 0..510, I cols 511..1021, pad 1022-1023
            transposeHL_kernel<<<dim3(16, 16, cb), tblk, 0, stream>>>(
                outRI, oRTH, oRTL, HW, HW, HW, 1024, 0, 511, 2L * HW2, sb_oRT);
            transposeHL_kernel<<<dim3(16, 17, cb), tblk, 0, stream>>>(
                outRI + HW2, oRTH, oRTL, HW, HW, HW, 1024, 511, 513, 2L * HW2, sb_oRT);

            // X = CS*[R;I] -> XY cols 0..510; Y = CS2*[R;I] -> cols 511..1021 (+zero 1022)
            gemmHL(CSH, CSL, 1024, 0, oRTH, oRTL, 1024, sb_oRT,
                   XYH, XYL, 1024, sb_XY, 510, 511, 511, 1024, 1.f);
            gemmHL(CS2H, CS2L, 1024, 0, oRTH, oRTL, 1024, sb_oRT,
                   XYH + 511, XYL + 511, 1024, sb_XY, 510, 511, 512, 1024, 1.f);
            // F = [X|Y] * CS^T (float)
            float* Ft = (t == 0) ? F1c : F2c;
            gemmF(XYH, XYL, 1024, sb_XY, CSH, CSL, 1024, 0,
                  Ft, MM, MM2, 510, 510, 1024, 1.f);
        }

        update_kernel<<<gridc, blk, 0, stream>>>(cur, coef, F1c, F2c, b0, dmode);
        norm_kernel<<<gridc, blk, 0, stream>>>(cur, f, coef, pb, b0, dmode);
        reduce_kernel<<<1, 256, 0, stream>>>(pb, (long)1024 * cb, acc);
    }

    finalize_kernel<<<1, 1, 0, stream>>>(acc, (float*)d_out);
}

// Round 12
// 967.985 us; speedup vs baseline: 9.2371x; 1.0870x over previous
//
#include <hip/hip_runtime.h>
#include <hip/hip_bf16.h>
#include <math.h>

#define HW   511
#define HW2  261121      // 511*511
#define MM   510
#define MM2  260100      // 510*510
#define NN   512
#define NN2  262144      // 512*512
#define PI_D 3.14159265358979323846

typedef __attribute__((ext_vector_type(8))) short short8;
typedef __attribute__((ext_vector_type(4))) float float4v;

__device__ __forceinline__ float bf2f(const __hip_bfloat16 v) { return __bfloat162float(v); }

__device__ __forceinline__ float ldin(const void* p, long i, int mode)
{
    return mode ? ((const float*)p)[i] : bf2f(((const __hip_bfloat16*)p)[i]);
}

__device__ __forceinline__ short f2bf(float v)
{
    unsigned u = __builtin_bit_cast(unsigned, v);
    u += 0x7FFF + ((u >> 16) & 1);
    return (short)(u >> 16);
}
__device__ __forceinline__ float bfs2f(short s)
{
    unsigned u = ((unsigned)(unsigned short)s) << 16;
    return __builtin_bit_cast(float, u);
}

__global__ void detect_kernel(const void* __restrict__ f, int* __restrict__ mode)
{
    __shared__ int cnt;
    if (threadIdx.x == 0) cnt = 0;
    __syncthreads();
    float v = ((const float*)f)[threadIdx.x];
    float a = fabsf(v);
    int sane = (isfinite(v) && a > 1e-6f && a < 100.f) ? 1 : 0;
    atomicAdd(&cnt, sane);
    __syncthreads();
    if (threadIdx.x == 0) mode[0] = (cnt >= 128) ? 1 : 0;
}

__global__ void sentinel_kernel(float* __restrict__ out) { out[0] = 0.25f; }

__global__ void zerod_kernel(double* __restrict__ p)
{
    if (threadIdx.x < 2) p[threadIdx.x] = 0.0;
}

// ---------------- basis matrices, directly as bf16 hi/lo planes ----------------
__global__ void basisHL_kernel(short* __restrict__ SfH, short* __restrict__ SfL,
                               short* __restrict__ CSH, short* __restrict__ CSL,
                               short* __restrict__ CS2H, short* __restrict__ CS2L)
{
    int idx = blockIdx.x * 256 + threadIdx.x;
    if (idx < 511 * 512) {
        int a = idx / 512, m = idx % 512;
        float v = 0.f;
        if (m < 510) v = (float)sin(PI_D * (double)(a - 255) * (double)(m + 1) / 511.0);
        short h = f2bf(v);
        SfH[idx] = h; SfL[idx] = f2bf(v - bfs2f(h));
    }
    if (idx < 510 * 1024) {
        int p = idx / 1024, a = idx % 1024;
        float c = 0.f, c2 = 0.f;
        if (a < 1022) {
            if (a < 511) {
                double ang = PI_D * (double)p * (double)(a - 255) / 511.0;
                c = (float)cos(ang); c2 = (float)(-sin(ang));
            } else {
                double ang = PI_D * (double)p * (double)(a - 511 - 255) / 511.0;
                c = (float)sin(ang); c2 = (float)cos(ang);
            }
        }
        short h = f2bf(c);
        CSH[idx] = h; CSL[idx] = f2bf(c - bfs2f(h));
        h = f2bf(c2);
        CS2H[idx] = h; CS2L[idx] = f2bf(c2 - bfs2f(h));
    }
}

__global__ void zerocol_kernel(short* __restrict__ XH, short* __restrict__ XL, long csb)
{
    int z = blockIdx.x;
    int t = threadIdx.x;
    if (t < 510) {
        XH[(long)z * csb + (long)t * 1024 + 1023] = 0;
        XL[(long)z * csb + (long)t * 1024 + 1023] = 0;
    }
}

// ---------------- 5-point stencil A ----------------
__device__ __forceinline__ float computeA(const float* __restrict__ xb,
                                          const void* __restrict__ cb,
                                          int p, int q, int mode)
{
    if (p < 1 || p > 510 || q < 1 || q > 510) return 0.f;
    int i = p - 1, j = q - 1;
    float a   = ldin(cb, (long)i * MM + j, mode);
    float aw  = ldin(cb, (long)i * MM + (j > 0 ? j - 1 : 0), mode);
    float ae  = ldin(cb, (long)i * MM + (j < MM - 1 ? j + 1 : MM - 1), mode);
    float an  = ldin(cb, (long)(i < MM - 1 ? i + 1 : MM - 1) * MM + j, mode);
    float as_ = ldin(cb, (long)(i > 0 ? i - 1 : 0) * MM + j, mode);
    float sw = -2.f * aw  * a / (aw  + a);
    float se = -2.f * ae  * a / (ae  + a);
    float sn = -2.f * an  * a / (an  + a);
    float ss = -2.f * as_ * a / (as_ + a);
    float sc = -(sw + se + sn + ss);
    return ss * xb[(p - 1) * NN + q] + sw * xb[p * NN + q - 1] + sc * xb[p * NN + q]
         + se * xb[p * NN + q + 1] + sn * xb[(p + 1) * NN + q];
}

__global__ void initx_kernel(float* __restrict__ x, const void* __restrict__ f,
                             int b0, const int* __restrict__ dmode)
{
    int mode = dmode[0];
    int q = blockIdx.x * 32 + threadIdx.x;
    int p = blockIdx.y * 8 + threadIdx.y;
    int bz = blockIdx.z;
    int b = b0 + bz;
    if (p >= NN || q >= NN) return;
    const char* fc = (const char*)f + ((long)b * NN2 << (mode + 1));
    x[(long)bz * NN2 + p * NN + q] = 0.078125f * ldin(fc, (long)p * NN + q, mode);
}

__global__ void rich_kernel(const float* __restrict__ xin, float* __restrict__ xout,
                            const void* __restrict__ f, const void* __restrict__ coef,
                            int b0, const int* __restrict__ dmode)
{
    int mode = dmode[0];
    int q = blockIdx.x * 32 + threadIdx.x;
    int p = blockIdx.y * 8 + threadIdx.y;
    int bz = blockIdx.z;
    int b = b0 + bz;
    if (p >= NN || q >= NN) return;
    long xo = (long)bz * NN2;
    const char* cc = (const char*)coef + ((long)b * MM2 << (mode + 1));
    const char* fc = (const char*)f + ((long)b * NN2 << (mode + 1));
    float Ax = computeA(xin + xo, cc, p, q, mode);
    float fv = ldin(fc, (long)p * NN + q, mode);
    xout[xo + p * NN + q] = xin[xo + p * NN + q] + 0.078125f * (fv - Ax);
}

__global__ void resid_kernel(const float* __restrict__ x,
                             const void* __restrict__ f, const void* __restrict__ coef,
                             float* __restrict__ r1, int b0, const int* __restrict__ dmode)
{
    int mode = dmode[0];
    int j = blockIdx.x * 32 + threadIdx.x;
    int i = blockIdx.y * 8 + threadIdx.y;
    int bz = blockIdx.z;
    int b = b0 + bz;
    if (i >= MM || j >= MM) return;
    int p = i + 1, q = j + 1;
    const char* cc = (const char*)coef + ((long)b * MM2 << (mode + 1));
    const char* fc = (const char*)f + ((long)b * NN2 << (mode + 1));
    float Ax = computeA(x + (long)bz * NN2, cc, p, q, mode);
    r1[(long)bz * MM2 + i * MM + j] = ldin(fc, (long)p * NN + q, mode) - Ax;
}

__global__ void update_kernel(float* __restrict__ x,
                              const void* __restrict__ coef,
                              const float* __restrict__ F1, const float* __restrict__ F2,
                              int b0, const int* __restrict__ dmode)
{
    int mode = dmode[0];
    int j = blockIdx.x * 32 + threadIdx.x;
    int i = blockIdx.y * 8 + threadIdx.y;
    int bz = blockIdx.z;
    int b = b0 + bz;
    if (i >= MM || j >= MM) return;
    float cf = ldin(coef, (long)b * MM2 + i * MM + j, mode);
    long o = (long)bz * MM2 + i * MM + j;
    float e = (cf < 1.0f) ? (F1[o] / cf) : (F2[o] * cf);
    x[(long)bz * NN2 + (i + 1) * NN + (j + 1)] += e;
}

__global__ void norm_kernel(const float* __restrict__ x,
                            const void* __restrict__ f, const void* __restrict__ coef,
                            double* __restrict__ pb, int b0, const int* __restrict__ dmode)
{
    int mode = dmode[0];
    int q = blockIdx.x * 32 + threadIdx.x;
    int p = blockIdx.y * 8 + threadIdx.y;
    int bz = blockIdx.z;
    int b = b0 + bz;
    double r2 = 0.0, f2 = 0.0;
    if (p < NN && q < NN) {
        const char* cc = (const char*)coef + ((long)b * MM2 << (mode + 1));
        const char* fc = (const char*)f + ((long)b * NN2 << (mode + 1));
        float Ax = computeA(x + (long)bz * NN2, cc, p, q, mode);
        float fv = ldin(fc, (long)p * NN + q, mode);
        float rv = fv - Ax;
        r2 = (double)rv * (double)rv;
        f2 = (double)fv * (double)fv;
    }
    for (int off = 32; off > 0; off >>= 1) {
        r2 += __shfl_down(r2, off, 64);
        f2 += __shfl_down(f2, off, 64);
    }
    __shared__ double sr[4], sf2[4];
    int tid = threadIdx.y * 32 + threadIdx.x;
    int wid = tid >> 6, lane = tid & 63;
    if (lane == 0) { sr[wid] = r2; sf2[wid] = f2; }
    __syncthreads();
    if (tid == 0) {
        long blk = ((long)blockIdx.z * gridDim.y + blockIdx.y) * gridDim.x + blockIdx.x;
        pb[2 * blk]     = sr[0] + sr[1] + sr[2] + sr[3];
        pb[2 * blk + 1] = sf2[0] + sf2[1] + sf2[2] + sf2[3];
    }
}

__global__ void reduce_kernel(const double* __restrict__ pb, long nblk, double* __restrict__ acc)
{
    double r2 = 0.0, f2 = 0.0;
    for (long i = threadIdx.x; i < nblk; i += 256) {
        r2 += pb[2 * i];
        f2 += pb[2 * i + 1];
    }
    for (int off = 32; off > 0; off >>= 1) {
        r2 += __shfl_down(r2, off, 64);
        f2 += __shfl_down(f2, off, 64);
    }
    __shared__ double sr[4], sf2[4];
    int wid = threadIdx.x >> 6, lane = threadIdx.x & 63;
    if (lane == 0) { sr[wid] = r2; sf2[wid] = f2; }
    __syncthreads();
    if (threadIdx.x == 0) {
        acc[0] += sr[0] + sr[1] + sr[2] + sr[3];
        acc[1] += sf2[0] + sf2[1] + sf2[2] + sf2[3];
    }
}

__global__ void finalize_kernel(const double* __restrict__ acc, float* __restrict__ out)
{
    out[0] = (float)sqrt(acc[0] / acc[1]);
}

// ---------------- fused transpose + hi/lo split ----------------
__global__ void transposeHL_kernel(const float* __restrict__ in,
                                   short* __restrict__ H, short* __restrict__ L,
                                   int R, int C, int ldin, int ldk, int kofs, int Rpad,
                                   long isb, long osb)
{
    __shared__ float t[32][33];
    int z = blockIdx.z;
    in += (long)z * isb;
    H += (long)z * osb + kofs;
    L += (long)z * osb + kofs;
    int c0 = blockIdx.x * 32, r0 = blockIdx.y * 32;
    for (int i = threadIdx.y; i < 32; i += 8) {
        int r = r0 + i, c = c0 + threadIdx.x;
        t[i][threadIdx.x] = (r < R && c < C) ? in[(long)r * ldin + c] : 0.f;
    }
    __syncthreads();
    for (int i = threadIdx.y; i < 32; i += 8) {
        int c = c0 + i, r = r0 + threadIdx.x;
        if (c < C && r < Rpad) {
            float v = t[threadIdx.x][i];
            short h = f2bf(v);
            H[(long)c * ldk + r] = h;
            L[(long)c * ldk + r] = f2bf(v - bfs2f(h));
        }
    }
}

// ---------------- MFMA GEMM on precomputed hi/lo planes ----------------
#define GM 64
#define GN 64
#define GK2 64
#define LK2 72
__global__ __launch_bounds__(256) void gemm_hl(
    const short* __restrict__ AH, const short* __restrict__ AL, int ldaS,
    const short* __restrict__ BH, const short* __restrict__ BL, int ldbS,
    float* __restrict__ C, int ldc,
    short* __restrict__ CH, short* __restrict__ CL, int ldcS, int Npad,
    int M, int N, int Kpad,
    long asb, long bsb, long csb, float alpha, int outHL)
{
    int z = blockIdx.z;
    AH += (long)z * asb; AL += (long)z * asb;
    BH += (long)z * bsb; BL += (long)z * bsb;
    if (outHL) { CH += (long)z * csb; CL += (long)z * csb; }
    else       { C  += (long)z * csb; }
    __shared__ short Ah[GM * LK2], Al[GM * LK2], Bh[GN * LK2], Bl[GN * LK2];
    int tid = threadIdx.x;
    int wave = tid >> 6, lane = tid & 63;
    int wm = (wave & 1) * 32, wn = (wave >> 1) * 32;
    int lr = lane & 15, lq = lane >> 4;
    int m0 = blockIdx.y * GM, n0 = blockIdx.x * GN;
    int row = tid >> 2, kk = (tid & 3) * 16;
    float4v acc[2][2] = {};
    short8 z8 = {};

    for (int k0 = 0; k0 < Kpad; k0 += GK2) {
        {
            short8 h0 = z8, h1 = z8, l0 = z8, l1 = z8;
            if (m0 + row < M) {
                long o = (long)(m0 + row) * ldaS + k0 + kk;
                h0 = *(const short8*)&AH[o]; h1 = *(const short8*)&AH[o + 8];
                l0 = *(const short8*)&AL[o]; l1 = *(const short8*)&AL[o + 8];
            }
            *(short8*)&Ah[row * LK2 + kk]     = h0;
            *(short8*)&Ah[row * LK2 + kk + 8] = h1;
            *(short8*)&Al[row * LK2 + kk]     = l0;
            *(short8*)&Al[row * LK2 + kk + 8] = l1;
        }
        {
            short8 h0 = z8, h1 = z8, l0 = z8, l1 = z8;
            if (n0 + row < N) {
                long o = (long)(n0 + row) * ldbS + k0 + kk;
                h0 = *(const short8*)&BH[o]; h1 = *(const short8*)&BH[o + 8];
                l0 = *(const short8*)&BL[o]; l1 = *(const short8*)&BL[o + 8];
            }
            *(short8*)&Bh[row * LK2 + kk]     = h0;
            *(short8*)&Bh[row * LK2 + kk + 8] = h1;
            *(short8*)&Bl[row * LK2 + kk]     = l0;
            *(short8*)&Bl[row * LK2 + kk + 8] = l1;
        }
        __syncthreads();
        #pragma unroll
        for (int ks = 0; ks < GK2; ks += 32) {
            short8 ah[2], al[2], bh[2], bl[2];
            #pragma unroll
            for (int mt = 0; mt < 2; ++mt) {
                int mloc = wm + mt * 16 + lr;
                ah[mt] = *(const short8*)&Ah[mloc * LK2 + ks + lq * 8];
                al[mt] = *(const short8*)&Al[mloc * LK2 + ks + lq * 8];
            }
            #pragma unroll
            for (int nt = 0; nt < 2; ++nt) {
                int nloc = wn + nt * 16 + lr;
                bh[nt] = *(const short8*)&Bh[nloc * LK2 + ks + lq * 8];
                bl[nt] = *(const short8*)&Bl[nloc * LK2 + ks + lq * 8];
            }
            #pragma unroll
            for (int mt = 0; mt < 2; ++mt)
                #pragma unroll
                for (int nt = 0; nt < 2; ++nt) {
                    acc[mt][nt] = __builtin_amdgcn_mfma_f32_16x16x32_bf16(ah[mt], bh[nt], acc[mt][nt], 0, 0, 0);
                    acc[mt][nt] = __builtin_amdgcn_mfma_f32_16x16x32_bf16(ah[mt], bl[nt], acc[mt][nt], 0, 0, 0);
                    acc[mt][nt] = __builtin_amdgcn_mfma_f32_16x16x32_bf16(al[mt], bh[nt], acc[mt][nt], 0, 0, 0);
                }
        }
        __syncthreads();
    }
    #pragma unroll
    for (int mt = 0; mt < 2; ++mt)
        #pragma unroll
        for (int nt = 0; nt < 2; ++nt)
            #pragma unroll
            for (int r = 0; r < 4; ++r) {
                int gm = m0 + wm + mt * 16 + lq * 4 + r;
                int gn = n0 + wn + nt * 16 + lr;
                if (gm >= M) continue;
                if (!outHL) {
                    if (gn < N) C[(long)gm * ldc + gn] = alpha * acc[mt][nt][r];
                } else {
                    if (gn < Npad) {
                        float v = (gn < N) ? alpha * acc[mt][nt][r] : 0.f;
                        short h = f2bf(v);
                        CH[(long)gm * ldcS + gn] = h;
                        CL[(long)gm * ldcS + gn] = f2bf(v - bfs2f(h));
                    }
                }
            }
}

// ---------------- complex 3x3 conv v5: 4 rows/thread + register weights ----------------
// Block (64,4) -> 64x16 output tile. Halo tile 18x66 float2 in LDS.
// Per channel: weights LDS->regs once (9 x COUT float2), 6-row slide computes 4 outputs.
// INK: 0 real planar, 1 interleaved float2 (chan stride 2*HW2), 2 planar complex
// OUTK: 0 interleaved float2, 1 planar complex (+ optional theta)
template<int CIN, int COUT, int INK, int OUTK>
__global__ __launch_bounds__(256, 3) void cconv4(
    const float* __restrict__ in, const float* __restrict__ in2,
    const void* __restrict__ w_r, const void* __restrict__ w_i,
    float* __restrict__ out, float* __restrict__ out2,
    const void* __restrict__ th_r, const void* __restrict__ th_i,
    long in_bs, long out_bs, int tmode, int b0, const int* __restrict__ dmode)
{
    int mode = dmode[0];
    int bz = blockIdx.z;
    int b  = b0 + bz;
    __shared__ float2 sw[CIN][9][COUT];
    __shared__ float2 tile[18][66];
    int tid = threadIdx.y * 64 + threadIdx.x;
    if (tid < CIN * 9 * COUT) {
        int i = tid / (9 * COUT), rem = tid % (9 * COUT), t = rem / COUT, o = rem % COUT;
        int dy = t / 3, dx = t % 3;
        float r, im;
        if (!tmode) {
            long idx = (((long)b * COUT + o) * CIN + i) * 9 + t;
            r = ldin(w_r, idx, mode); im = ldin(w_i, idx, mode);
        } else {
            long idx = (((long)b * CIN + i) * COUT + o) * 9 + dx * 3 + dy;
            r = ldin(w_r, idx, mode); im = -ldin(w_i, idx, mode);
        }
        float2 wv; wv.x = r; wv.y = im;
        sw[i][t][o] = wv;
    }
    int x0 = blockIdx.x * 64, y0 = blockIdx.y * 16;
    int x = x0 + threadIdx.x;
    int ybase = y0 + threadIdx.y * 4;
    float accr[COUT][4] = {}, acci[COUT][4] = {};
    #pragma unroll 1
    for (int i = 0; i < CIN; ++i) {
        __syncthreads();   // WAR on tile + (i==0) weight visibility
        const float* pr = in + (long)bz * in_bs + (INK == 1 ? (long)i * 2 * HW2 : (long)i * HW2);
        const float* pi = (INK == 2) ? (in2 + (long)bz * in_bs + (long)i * HW2) : nullptr;
        for (int idx = tid; idx < 18 * 66; idx += 256) {
            int ly = idx / 66, lx = idx % 66;
            int gy = y0 - 1 + ly, gx = x0 - 1 + lx;
            float2 v; v.x = 0.f; v.y = 0.f;
            if (gy >= 0 && gy < HW && gx >= 0 && gx < HW) {
                long gi = (long)gy * HW + gx;
                if (INK == 0) v.x = pr[gi];
                else if (INK == 1) v = ((const float2*)pr)[gi];
                else { v.x = pr[gi]; v.y = pi[gi]; }
            }
            tile[ly][lx] = v;
        }
        __syncthreads();
        // weights for this channel -> registers (contiguous in o => vector ds_read)
        float2 w[9][COUT];
        #pragma unroll
        for (int t = 0; t < 9; ++t)
            #pragma unroll
            for (int o = 0; o < COUT; ++o)
                w[t][o] = sw[i][t][o];
        // slide over 6 input rows -> 4 output rows
        #pragma unroll
        for (int ry = 0; ry < 6; ++ry) {
            float2 v[3];
            #pragma unroll
            for (int d = 0; d < 3; ++d)
                v[d] = tile[threadIdx.y * 4 + ry][threadIdx.x + d];
            #pragma unroll
            for (int k = 0; k < 4; ++k) {
                int dy = ry - k;
                if (dy < 0 || dy > 2) continue;
                #pragma unroll
                for (int dx = 0; dx < 3; ++dx) {
                    #pragma unroll
                    for (int o = 0; o < COUT; ++o) {
                        float2 wv = w[dy * 3 + dx][o];
                        accr[o][k] += v[dx].x * wv.x;
                        acci[o][k] += v[dx].x * wv.y;
                        if (INK != 0) {
                            accr[o][k] -= v[dx].y * wv.y;
                            acci[o][k] += v[dx].y * wv.x;
                        }
                    }
                }
            }
        }
    }
    if (x >= HW) return;
    #pragma unroll
    for (int k = 0; k < 4; ++k) {
        int y = ybase + k;
        if (y >= HW) continue;
        #pragma unroll
        for (int o = 0; o < COUT; ++o) {
            float ar = accr[o][k], ai = acci[o][k];
            if (th_r) {
                float tr = ldin(th_r, (long)b * HW2 + (long)y * HW + x, mode);
                float ti = ldin(th_i, (long)b * HW2 + (long)y * HW + x, mode);
                float nr = ar * tr - ai * ti, ni = ar * ti + ai * tr;
                ar = nr; ai = ni;
            }
            if (OUTK == 0) {
                float2 v; v.x = ar; v.y = ai;
                ((float2*)(out + (long)bz * out_bs + (long)o * 2 * HW2))[(long)y * HW + x] = v;
            } else {
                long oo = (long)bz * out_bs + (long)o * HW2 + (long)y * HW + x;
                out[oo]  = ar;
                out2[oo] = ai;
            }
        }
    }
}

extern "C" void kernel_launch(void* const* d_in, const int* in_sizes, int n_in,
                              void* d_out, int out_size, void* d_ws, size_t ws_size,
                              hipStream_t stream)
{
    const void* f    = d_in[0];
    const void* coef = d_in[1];
    const void* W1r[2] = {d_in[2],  d_in[8]};
    const void* W1i[2] = {d_in[3],  d_in[9]};
    const void* W2r[2] = {d_in[4],  d_in[10]};
    const void* W2i[2] = {d_in[5],  d_in[11]};
    const void* W3r[2] = {d_in[6],  d_in[12]};
    const void* W3i[2] = {d_in[7],  d_in[13]};
    const void* THr[2] = {d_in[14], d_in[16]};
    const void* THi[2] = {d_in[15], d_in[17]};

    sentinel_kernel<<<1, 64, 0, stream>>>((float*)d_out);

    // ---- ws accounting ----
    const size_t PERSIST = 1330000;
    const size_t PERB    = 7900000;
    size_t ws_floats = ws_size / sizeof(float);
    int cb = 8;
    while (cb > 1 && PERSIST + (size_t)cb * PERB > ws_floats) cb >>= 1;

    float* ws = (float*)d_ws;
    size_t off = 0;
    auto alloc = [&](size_t n) { size_t o = off; off += (n + 63) & ~(size_t)63; return ws + o; };
    auto salloc = [&](size_t nshorts) { return (short*)alloc((nshorts + 1) / 2); };
    double* acc  = (double*)alloc(64);
    int*   dmode = (int*)alloc(64);
    double* pb   = (double*)alloc(32768);
    short* SfH  = salloc(511L * 512); short* SfL  = salloc(511L * 512);
    short* CSH  = salloc(510L * 1024); short* CSL  = salloc(510L * 1024);
    short* CS2H = salloc(510L * 1024); short* CS2L = salloc(510L * 1024);
    float* xcur = alloc((size_t)cb * NN2);
    float* xnxt = alloc((size_t)cb * NN2);
    float* r1   = alloc((size_t)cb * MM2);
    float* F1c  = alloc((size_t)cb * MM2);
    float* F2c  = alloc((size_t)cb * MM2);
    float* G    = alloc((size_t)cb * HW2);
    float* outRI  = alloc((size_t)cb * 2 * HW2);
    float* bufA = alloc((size_t)cb * 8 * HW2);
    float* bufB = alloc((size_t)cb * 8 * HW2);
    short* r1TH = salloc((size_t)cb * 510 * 512); short* r1TL = salloc((size_t)cb * 510 * 512);
    short* T1H  = salloc((size_t)cb * 511 * 512); short* T1L  = salloc((size_t)cb * 511 * 512);
    short* oRTH = salloc((size_t)cb * 511 * 1024); short* oRTL = salloc((size_t)cb * 511 * 1024);
    short* XYH  = salloc((size_t)cb * 510 * 1024); short* XYL  = salloc((size_t)cb * 510 * 1024);

    detect_kernel<<<1, 256, 0, stream>>>(f, dmode);
    zerod_kernel<<<1, 64, 0, stream>>>(acc);
    basisHL_kernel<<<dim3((510 * 1024 + 255) / 256), 256, 0, stream>>>(SfH, SfL, CSH, CSL, CS2H, CS2L);

    dim3 blk(32, 8);
    dim3 gridc(16, 64, cb);
    dim3 cblk(64, 4);
    dim3 cgrid(8, 32, cb);     // 64x16 tiles over 511x511
    dim3 tblk(32, 8);

    const long sb_r1T = 510L * 512, sb_T1 = 511L * 512, sb_oRT = 511L * 1024, sb_XY = 510L * 1024;
    const float cfwd = -4.0f / 1044484.0f;  // -4/1022^2

    auto gemmF = [&](const short* AH_, const short* AL_, int ldaS, long asb,
                     const short* BH_, const short* BL_, int ldbS, long bsb,
                     float* C_, int ldc, long csb,
                     int M, int N, int Kpad, float alpha) {
        dim3 g((N + GN - 1) / GN, (M + GM - 1) / GM, cb);
        gemm_hl<<<g, 256, 0, stream>>>(AH_, AL_, ldaS, BH_, BL_, ldbS,
                                       C_, ldc, nullptr, nullptr, 0, 0,
                                       M, N, Kpad, asb, bsb, csb, alpha, 0);
    };
    auto gemmHL = [&](const short* AH_, const short* AL_, int ldaS, long asb,
                      const short* BH_, const short* BL_, int ldbS, long bsb,
                      short* CH_, short* CL_, int ldcS, long csb,
                      int M, int N, int Npad, int Kpad, float alpha) {
        dim3 g((Npad + GN - 1) / GN, (M + GM - 1) / GM, cb);
        gemm_hl<<<g, 256, 0, stream>>>(AH_, AL_, ldaS, BH_, BL_, ldbS,
                                       nullptr, 0, CH_, CL_, ldcS, Npad,
                                       M, N, Kpad, asb, bsb, csb, alpha, 1);
    };

    for (int b0 = 0; b0 < 8; b0 += cb) {
        initx_kernel<<<gridc, blk, 0, stream>>>(xcur, f, b0, dmode);
        float* cur = xcur; float* nxt = xnxt;
        for (int it = 0; it < 9; ++it) {
            rich_kernel<<<gridc, blk, 0, stream>>>(cur, nxt, f, coef, b0, dmode);
            float* t = cur; cur = nxt; nxt = t;
        }
        resid_kernel<<<gridc, blk, 0, stream>>>(cur, f, coef, r1, b0, dmode);

        transposeHL_kernel<<<dim3(16, 16, cb), tblk, 0, stream>>>(
            r1, r1TH, r1TL, MM, MM, MM, 512, 0, 512, MM2, sb_r1T);

        gemmHL(SfH, SfL, 512, 0, r1TH, r1TL, 512, sb_r1T,
               T1H, T1L, 512, sb_T1, 511, 510, 512, 512, 1.f);
        gemmF(T1H, T1L, 512, sb_T1, SfH, SfL, 512, 0,
              G, HW, HW2, 511, 511, 512, cfwd);

        zerocol_kernel<<<cb, 512, 0, stream>>>(XYH, XYL, sb_XY);

        for (int t = 0; t < 2; ++t) {
            cconv4<1, 4, 0, 0><<<cgrid, cblk, 0, stream>>>(
                G, nullptr, W1r[t], W1i[t], bufA, nullptr, nullptr, nullptr,
                HW2, 8L * HW2, 0, b0, dmode);
            cconv4<4, 4, 1, 0><<<cgrid, cblk, 0, stream>>>(
                bufA, nullptr, W2r[t], W2i[t], bufB, nullptr, nullptr, nullptr,
                8L * HW2, 8L * HW2, 0, b0, dmode);
            cconv4<4, 1, 1, 1><<<cgrid, cblk, 0, stream>>>(
                bufB, nullptr, W3r[t], W3i[t], outRI, outRI + HW2, THr[t], THi[t],
                8L * HW2, 2L * HW2, 0, b0, dmode);
            cconv4<1, 4, 2, 0><<<cgrid, cblk, 0, stream>>>(
                outRI, outRI + HW2, W3r[t], W3i[t], bufA, nullptr, nullptr, nullptr,
                2L * HW2, 8L * HW2, 1, b0, dmode);
            cconv4<4, 4, 1, 0><<<cgrid, cblk, 0, stream>>>(
                bufA, nullptr, W2r[t], W2i[t], bufB, nullptr, nullptr, nullptr,
                8L * HW2, 8L * HW2, 1, b0, dmode);
            cconv4<4, 1, 1, 1><<<cgrid, cblk, 0, stream>>>(
                bufB, nullptr, W1r[t], W1i[t], outRI, outRI + HW2, nullptr, nullptr,
                8L * HW2, 2L * HW2, 1, b0, dmode);

            transposeHL_kernel<<<dim3(16, 16, cb), tblk, 0, stream>>>(
                outRI, oRTH, oRTL, HW, HW, HW, 1024, 0, 511, 2L * HW2, sb_oRT);
            transposeHL_kernel<<<dim3(16, 17, cb), tblk, 0, stream>>>(
                outRI + HW2, oRTH, oRTL, HW, HW, HW, 1024, 511, 513, 2L * HW2, sb_oRT);

            gemmHL(CSH, CSL, 1024, 0, oRTH, oRTL, 1024, sb_oRT,
                   XYH, XYL, 1024, sb_XY, 510, 511, 511, 1024, 1.f);
            gemmHL(CS2H, CS2L, 1024, 0, oRTH, oRTL, 1024, sb_oRT,
                   XYH + 511, XYL + 511, 1024, sb_XY, 510, 511, 512, 1024, 1.f);
            float* Ft = (t == 0) ? F1c : F2c;
            gemmF(XYH, XYL, 1024, sb_XY, CSH, CSL, 1024, 0,
                  Ft, MM, MM2, 510, 510, 1024, 1.f);
        }

        update_kernel<<<gridc, blk, 0, stream>>>(cur, coef, F1c, F2c, b0, dmode);
        norm_kernel<<<gridc, blk, 0, stream>>>(cur, f, coef, pb, b0, dmode);
        reduce_kernel<<<1, 256, 0, stream>>>(pb, (long)1024 * cb, acc);
    }

    finalize_kernel<<<1, 1, 0, stream>>>(acc, (float*)d_out);
}